// Round 9
// baseline (3029.142 us; speedup 1.0000x reference)
//
#include <hip/hip_runtime.h>
#include <math.h>

typedef short bf16x8 __attribute__((ext_vector_type(8)));
typedef float f32x4 __attribute__((ext_vector_type(4)));

#define B 8
#define NS 4096
#define NC 256
#define TH 8
#define TP 24
#define T_ALL 32
#define DIN 28
#define DM 27
#define G 64
#define H 64
#define NG3 192
#define NSTEP 31

#define NTHR 256
// phase-B geometry: 1024 blocks, 4 blocks/CU (verified round-5/8)
#define NBLK_B 1024
#define SROWS 32          // station rows per B-block
#define CROWS 2           // city rows per B-block
// phase-A geometry (precomp / fallback grid)
#define NBLK_A 2048
#define AS 16             // station rows per A-block
#define AR 17             // +1 city row

// xcat K layout: 0..27 x | 28..91 own_xg | 92..155 buf | 156..219 h | 220 bias | 221..223 pad
#define XCW 224
#define KIT 7             // K-iters of 32
#define NT 16             // N tiles (256 gate cols)
#define WFRAG (KIT*NT*64*8)   // 57344 bf16 per weight array
#define CVFRAG (2*4*64*8)     // 4096 bf16 per conv-weight array (K=64, N=64)

#define WS_ELL 64
#define WF_ELL 32
#define WFT_ELL 128

struct Params {
  const float *x_hist, *feat_s, *c_x_hist, *feat_c, *adj_s, *adj_c, *afc;
  const float *conv_w, *conv_b, *c_conv_w, *c_conv_b;
  const float *gru_wi, *gru_wh, *gru_bi, *gru_bh;
  const float *c_gru_wi, *c_gru_wh, *c_gru_bi, *c_gru_bh;
  const float *fc_w, *fc_b, *c_fc_w, *c_fc_b;
  const float *c2s_w, *c2s_b, *s2c_w, *s2c_b;
  int *deg_s, *ellc_s; float *ellv_s, *dinv_s;
  int *deg_c, *ellc_c; float *ellv_c, *dinv_c;
  int *degf, *ellf;
  int *degfT, *ellfT;
  float *xg_s, *xg_c, *xp_s, *xp_c;
  unsigned short *xsh, *xsl;         // [B*NS][XCW] bf16 hi/lo (pre-split A matrix)
  unsigned short *xch, *xcl;         // [B*NC][XCW] bf16 hi/lo
  unsigned short *wSh, *wSl, *wCh, *wCl;  // fragment-ordered Wcat2 bf16 hi/lo
  unsigned short *wcvSh, *wcvSl, *wcvCh, *wcvCl; // conv-weight fragments [K=64 x N=64]
  float *aA_s, *aA_c;                // [NSTEP][nodes][G]: hist->xg, pred->conv partial
  float *out;
};

__device__ __forceinline__ float sigm_(float x) { return 1.0f / (1.0f + expf(-x)); }

__device__ __forceinline__ unsigned short bf16rn(float f) {
  unsigned u = __float_as_uint(f);
  u += 0x7fffu + ((u >> 16) & 1u);
  return (unsigned short)(u >> 16);
}
__device__ __forceinline__ float bf16tof(unsigned short h) {
  return __uint_as_float(((unsigned)h) << 16);
}
__device__ __forceinline__ void split1(float f, unsigned short& hi, unsigned short& lo) {
  hi = bf16rn(f);
  lo = bf16rn(f - bf16tof(hi));
}

// LDS swizzle for precompA2 (kept from round 8: conflicts 1.7e7 -> 2.3e6)
__device__ __forceinline__ int sidx(int i, int c) {
  return i * 64 + (c ^ ((i & 7) << 3));
}

// 16-wide gather round: 4 int4 index loads + 4 float4 coeff loads + 16
// independent strided feat loads. ELL padded (c=0, v=0) so trip rounds to 16.
__device__ __forceinline__ float gather16(const float* base, size_t stride,
                                          const int* cc, const float* vv, int trip) {
  float acc = 0.0f;
  for (int e = 0; e < trip; e += 16) {
    int4 c0 = *(const int4*)&cc[e];
    int4 c1 = *(const int4*)&cc[e + 4];
    int4 c2 = *(const int4*)&cc[e + 8];
    int4 c3 = *(const int4*)&cc[e + 12];
    float4 v0 = *(const float4*)&vv[e];
    float4 v1 = *(const float4*)&vv[e + 4];
    float4 v2 = *(const float4*)&vv[e + 8];
    float4 v3 = *(const float4*)&vv[e + 12];
    float x0 = base[(size_t)c0.x * stride], x1 = base[(size_t)c0.y * stride];
    float x2 = base[(size_t)c0.z * stride], x3 = base[(size_t)c0.w * stride];
    float x4 = base[(size_t)c1.x * stride], x5 = base[(size_t)c1.y * stride];
    float x6 = base[(size_t)c1.z * stride], x7 = base[(size_t)c1.w * stride];
    float x8 = base[(size_t)c2.x * stride], x9 = base[(size_t)c2.y * stride];
    float xa = base[(size_t)c2.z * stride], xb = base[(size_t)c2.w * stride];
    float xc = base[(size_t)c3.x * stride], xd = base[(size_t)c3.y * stride];
    float xe = base[(size_t)c3.z * stride], xf = base[(size_t)c3.w * stride];
    acc += v0.x * x0 + v0.y * x1 + v0.z * x2 + v0.w * x3
         + v1.x * x4 + v1.y * x5 + v1.z * x6 + v1.w * x7
         + v2.x * x8 + v2.y * x9 + v2.z * xa + v2.w * xb
         + v3.x * xc + v3.y * xd + v3.z * xe + v3.w * xf;
  }
  return acc;
}

// Original Wcat[k][c], k in 0..156: rows 0..91 = wi, 92..155 = wh, 156 = bias.
// cols 0..127 = r,z (x+h fused); 128..191 = xn (wi only); 192..255 = hc (wh only).
__device__ float wcat_val(int k, int c, const float* wi, const float* wh,
                          const float* bi, const float* bh) {
  if (k < 92)  { return (c < 192) ? wi[k * NG3 + c] : 0.0f; }
  if (k < 156) {
    int kk = k - 92;
    if (c < 128) return wh[kk * NG3 + c];
    if (c < 192) return 0.0f;
    return wh[kk * NG3 + (c - 64)];
  }
  if (k == 156) {
    if (c < 128) return bi[c] + bh[c];
    if (c < 192) return bi[c];
    return bh[c - 64];
  }
  return 0.0f;
}

// Extended Wcat2[k][c], k in 0..223, folding the fuse stage.
__device__ float wcat2_val(int k, int c, const float* wi, const float* wh,
                           const float* bi, const float* bh,
                           const float* wm, const float* bm) {
  if (k < 92) return wcat_val(k, c, wi, wh, bi, bh);
  if (k < 156) {
    int f = k - 92;
    float s = 0.0f;
    for (int g = 0; g < G; g++)
      s += wm[f * G + g] * wcat_val(28 + g, c, wi, wh, bi, bh);
    return s;
  }
  if (k < 220) return wcat_val(92 + (k - 156), c, wi, wh, bi, bh);
  if (k == 220) {
    float s = wcat_val(156, c, wi, wh, bi, bh);
    for (int g = 0; g < G; g++)
      s += bm[g] * wcat_val(28 + g, c, wi, wh, bi, bh);
    return s;
  }
  return 0.0f;
}

// x channel f of node n at global step (fallback stepA only).
__device__ __forceinline__ float xval(const Params& p, int sta, int hist, int step,
                                      int b, int n, int f) {
  if (f == 0) {
    if (hist) return sta ? p.x_hist[((size_t)b * TH + step) * NS + n]
                         : p.c_x_hist[((size_t)b * TH + step) * NC + n];
    return sta ? p.xp_s[b * NS + n] : p.xp_c[b * NC + n];
  }
  int tf = step + 1;
  return sta ? p.feat_s[(((size_t)b * T_ALL + tf) * NS + n) * DM + (f - 1)]
             : p.feat_c[(((size_t)b * T_ALL + tf) * NC + n) * DM + (f - 1)];
}

// ---------------- P0: ELL tables + weight fragment prep + xcat init ----------------
__device__ void build_tables(const Params& p, int bid, int tid, int nblk) {
  const int lane = tid & 63;
  const int gw = bid * 4 + (tid >> 6);
  const int nw = nblk * 4;

  for (int r = gw; r < NS; r += nw) {
    int base = 0;
    for (int n0 = 0; n0 < NS; n0 += 64) {
      int n = n0 + lane;
      float v = p.adj_s[(size_t)r * NS + n];
      bool fl = (v != 0.0f) && (n != r);
      unsigned long long m = __ballot(fl);
      if (fl) {
        int pos = base + (int)__popcll(m & ((1ull << lane) - 1ull));
        if (pos < WS_ELL) p.ellc_s[r * WS_ELL + pos] = n;
      }
      base += (int)__popcll(m);
    }
    int deg = base < WS_ELL ? base : WS_ELL;
    for (int s = deg + lane; s < WS_ELL; s += 64) p.ellc_s[r * WS_ELL + s] = 0;
    if (lane == 0) {
      p.deg_s[r] = deg;
      p.dinv_s[r] = base > 0 ? 1.0f / sqrtf((float)base) : 0.0f;
    }
  }
  for (int r = gw; r < NS; r += nw) {
    int base = 0;
    for (int n0 = 0; n0 < NC; n0 += 64) {
      int n = n0 + lane;
      bool fl = p.afc[(size_t)r * NC + n] != 0.0f;
      unsigned long long m = __ballot(fl);
      if (fl) {
        int pos = base + (int)__popcll(m & ((1ull << lane) - 1ull));
        if (pos < WF_ELL) p.ellf[r * WF_ELL + pos] = n;
      }
      base += (int)__popcll(m);
    }
    int deg = base < WF_ELL ? base : WF_ELL;
    for (int s = deg + lane; s < WF_ELL; s += 64) p.ellf[r * WF_ELL + s] = 0;
    if (lane == 0) p.degf[r] = deg;
  }
  for (int r = gw; r < NC; r += nw) {
    int base = 0;
    for (int n0 = 0; n0 < NC; n0 += 64) {
      int n = n0 + lane;
      float v = p.adj_c[(size_t)r * NC + n];
      bool fl = (v != 0.0f) && (n != r);
      unsigned long long m = __ballot(fl);
      if (fl) {
        int pos = base + (int)__popcll(m & ((1ull << lane) - 1ull));
        if (pos < WS_ELL) p.ellc_c[r * WS_ELL + pos] = n;
      }
      base += (int)__popcll(m);
    }
    int deg = base < WS_ELL ? base : WS_ELL;
    for (int s = deg + lane; s < WS_ELL; s += 64) p.ellc_c[r * WS_ELL + s] = 0;
    if (lane == 0) {
      p.deg_c[r] = deg;
      p.dinv_c[r] = base > 0 ? 1.0f / sqrtf((float)base) : 0.0f;
    }
  }
  for (int r = gw; r < NC; r += nw) {
    int base = 0;
    for (int n0 = 0; n0 < NS; n0 += 64) {
      int n = n0 + lane;
      bool fl = p.afc[(size_t)n * NC + r] != 0.0f;
      unsigned long long m = __ballot(fl);
      if (fl) {
        int pos = base + (int)__popcll(m & ((1ull << lane) - 1ull));
        if (pos < WFT_ELL) p.ellfT[r * WFT_ELL + pos] = n;
      }
      base += (int)__popcll(m);
    }
    int deg = base < WFT_ELL ? base : WFT_ELL;
    for (int s = deg + lane; s < WFT_ELL; s += 64) p.ellfT[r * WFT_ELL + s] = 0;
    if (lane == 0) p.degfT[r] = deg;
  }

  const int gid = bid * NTHR + tid, ntot = nblk * NTHR;
  // xp holds x_prev for the first pred step (= x_hist[:, TH-1])
  for (int i = gid; i < B * NS; i += ntot)
    p.xp_s[i] = p.x_hist[((size_t)(i / NS) * TH + (TH - 1)) * NS + (i % NS)];
  for (int i = gid; i < B * NC; i += ntot)
    p.xp_c[i] = p.c_x_hist[((size_t)(i / NC) * TH + (TH - 1)) * NC + (i % NC)];

  // GRU weight fragments: u -> (kiter q, tile t, lane l, j); k = q*32 + (l>>4)*8 + j
  for (int u = gid; u < WFRAG; u += ntot) {
    int j = u & 7, l = (u >> 3) & 63, t = (u >> 9) & 15, q = u >> 13;
    int k = q * 32 + ((l >> 4) << 3) + j;
    int c = t * 16 + (l & 15);
    float ws = wcat2_val(k, c, p.gru_wi, p.gru_wh, p.gru_bi, p.gru_bh, p.c2s_w, p.c2s_b);
    unsigned short hh, ll;
    split1(ws, hh, ll);
    p.wSh[u] = hh; p.wSl[u] = ll;
    float wc = wcat2_val(k, c, p.c_gru_wi, p.c_gru_wh, p.c_gru_bi, p.c_gru_bh, p.s2c_w, p.s2c_b);
    split1(wc, hh, ll);
    p.wCh[u] = hh; p.wCl[u] = ll;
  }
  // conv weight fragments (K=64: 0..27 = W0, 28..55 = W1, 56..63 = 0; N=64).
  for (int u = gid; u < CVFRAG; u += ntot) {
    int j = u & 7, l = (u >> 3) & 63, t = (u >> 9) & 3, q = u >> 11;
    int k = q * 32 + ((l >> 4) << 3) + j;
    int c = t * 16 + (l & 15);
    float vs = (k < 56) ? p.conv_w[k * G + c] : 0.0f;
    unsigned short hh, ll;
    split1(vs, hh, ll);
    p.wcvSh[u] = hh; p.wcvSl[u] = ll;
    float vc = (k < 56) ? p.c_conv_w[k * G + c] : 0.0f;
    split1(vc, hh, ll);
    p.wcvCh[u] = hh; p.wcvCl[u] = ll;
  }
  // xcat init: zeros (h state!), col 220 = 1.0 (bias)
  for (int u = gid; u < B * NS * XCW; u += ntot) {
    p.xsh[u] = ((u % XCW) == 220) ? 0x3F80 : 0;
    p.xsl[u] = 0;
  }
  for (int u = gid; u < B * NC * XCW; u += ntot) {
    p.xch[u] = ((u % XCW) == 220) ? 0x3F80 : 0;
    p.xcl[u] = 0;
  }
}

__device__ void ellv_fill(const Params& p, int gid, int ntot) {
  for (int s = gid; s < NS * WS_ELL; s += ntot) {
    int r = s >> 6, k = s & (WS_ELL - 1);
    p.ellv_s[s] = (k < p.deg_s[r]) ? -p.dinv_s[r] * p.dinv_s[p.ellc_s[s]] : 0.0f;
  }
  for (int s = gid; s < NC * WS_ELL; s += ntot) {
    int r = s >> 6, k = s & (WS_ELL - 1);
    p.ellv_c[s] = (k < p.deg_c[r]) ? -p.dinv_c[r] * p.dinv_c[p.ellc_c[s]] : 0.0f;
  }
}

// ---------------- precompA2: step-static cheb gather + MFMA conv for ALL steps ----------------
// Gather uses 16-wide rounds (gather16) for MLP: round-8 counters showed VGPR=32 /
// occupancy 91% / HBM 17% -> MLP-starved at max occupancy; spend registers instead.
__global__ __launch_bounds__(NTHR) void precompA2_kernel(Params p) {
  __shared__ unsigned short lh[AR * 64];
  __shared__ unsigned short llo[AR * 64];
  const int bid = blockIdx.x & 2047;
  const int step = blockIdx.x >> 11;
  const int hist = (step < TH - 1) ? 1 : 0;
  const int tid = threadIdx.x;
  const int b = bid >> 8;              // uniform per block

  // zero K-pad cols 56..63
  for (int u = tid; u < AR * 8; u += NTHR) {
    lh[sidx(u >> 3, 56 + (u & 7))] = 0;
    llo[sidx(u >> 3, 56 + (u & 7))] = 0;
  }

  for (int q = tid; q < AR * DIN; q += NTHR) {
    int i = q / DIN, f = q % DIN;
    int sta = (i < AS);
    int n;
    const int* cc; const float* vv; int trip;
    if (sta) {
      n = (bid * AS + i) & 4095;
      cc = &p.ellc_s[n * WS_ELL]; vv = &p.ellv_s[n * WS_ELL];
      trip = (p.deg_s[n] + 15) & ~15;
    } else {
      n = bid & 255;
      cc = &p.ellc_c[n * WS_ELL]; vv = &p.ellv_c[n * WS_ELL];
      trip = (p.deg_c[n] + 15) & ~15;
    }
    float xv = 0.0f, acc = 0.0f;
    if (f == 0) {
      if (hist) {
        const float* bh = sta ? (p.x_hist + ((size_t)b * TH + step) * NS)
                              : (p.c_x_hist + ((size_t)b * TH + step) * NC);
        xv = bh[n];
        acc = gather16(bh, 1, cc, vv, trip);
      }
      // pred: xv = acc = 0 (f=0 terms added per step in stepA_lite)
    } else {
      const float* bf = sta
        ? (p.feat_s + ((size_t)(b * T_ALL + step + 1) * NS) * DM + (f - 1))
        : (p.feat_c + ((size_t)(b * T_ALL + step + 1) * NC) * DM + (f - 1));
      xv = bf[(size_t)n * DM];
      acc = gather16(bf, DM, cc, vv, trip);
    }
    unsigned short hh, ll;
    split1(xv, hh, ll);
    lh[sidx(i, f)] = hh; llo[sidx(i, f)] = ll;
    split1(acc, hh, ll);
    lh[sidx(i, 28 + f)] = hh; llo[sidx(i, 28 + f)] = ll;
  }
  __syncthreads();

  // MFMA conv: wave wv owns output cols [wv*16, wv*16+16).
  const int l = tid & 63;
  const int wv = tid >> 6;
  f32x4 a1; f32x4 a2;
  a1[0] = 0.f; a1[1] = 0.f; a1[2] = 0.f; a1[3] = 0.f;
  a2[0] = 0.f; a2[1] = 0.f; a2[2] = 0.f; a2[3] = 0.f;
  const bf16x8* WVSh = (const bf16x8*)p.wcvSh;
  const bf16x8* WVSl = (const bf16x8*)p.wcvSl;
  const bf16x8* WVCh = (const bf16x8*)p.wcvCh;
  const bf16x8* WVCl = (const bf16x8*)p.wcvCl;
#pragma unroll
  for (int q = 0; q < 2; q++) {
    int kc = q * 32 + ((l >> 4) << 3);
    bf16x8 xh = *(const bf16x8*)&lh[sidx(l & 15, kc)];
    bf16x8 xl = *(const bf16x8*)&llo[sidx(l & 15, kc)];
    bf16x8 ch_, cl_;
    if ((l & 15) == 0) {
      ch_ = *(const bf16x8*)&lh[sidx(AS, kc)];
      cl_ = *(const bf16x8*)&llo[sidx(AS, kc)];
    } else {
#pragma unroll
      for (int j = 0; j < 8; j++) { ch_[j] = 0; cl_[j] = 0; }
    }
    int u = (q * 4 + wv) * 64 + l;
    bf16x8 bh_ = WVSh[u];
    bf16x8 bl_ = WVSl[u];
    a1 = __builtin_amdgcn_mfma_f32_16x16x32_bf16(xh, bh_, a1, 0, 0, 0);
    a1 = __builtin_amdgcn_mfma_f32_16x16x32_bf16(xl, bh_, a1, 0, 0, 0);
    a1 = __builtin_amdgcn_mfma_f32_16x16x32_bf16(xh, bl_, a1, 0, 0, 0);
    bf16x8 gh_ = WVCh[u];
    bf16x8 gl_ = WVCl[u];
    a2 = __builtin_amdgcn_mfma_f32_16x16x32_bf16(ch_, gh_, a2, 0, 0, 0);
    a2 = __builtin_amdgcn_mfma_f32_16x16x32_bf16(cl_, gh_, a2, 0, 0, 0);
    a2 = __builtin_amdgcn_mfma_f32_16x16x32_bf16(ch_, gl_, a2, 0, 0, 0);
  }

  const int g = wv * 16 + (l & 15);
  float* dst_s = p.aA_s + (size_t)step * (B * NS * G);
  float* dst_c = p.aA_c + (size_t)step * (B * NC * G);
  float bias = p.conv_b[g];
#pragma unroll
  for (int r = 0; r < 4; r++) {
    int row = ((l >> 4) << 2) + r;     // 0..15
    float v = a1[r] + bias;
    if (hist) v = sigm_(v);
    dst_s[(size_t)(bid * AS + row) * G + g] = v;
  }
  if ((l >> 4) == 0) {                  // city: C row 0 lives in lanes 0..15, reg 0
    float v = a2[0] + p.c_conv_b[g];
    if (hist) v = sigm_(v);
    dst_c[(size_t)bid * G + g] = v;
  }
}

// ---------------- stepA_lite: per-step dynamic completion ----------------
__global__ __launch_bounds__(NTHR) void stepA_lite_kernel(Params p, int step, int hist) {
  const int tid = threadIdx.x;
  const int l = tid & 63, wv = tid >> 6;
  const int wid = blockIdx.x * 4 + wv;
  if (wid < B * NS) {
    const int smn = wid, b = smn >> 12, n = smn & 4095;
    float x0 = hist ? p.x_hist[((size_t)b * TH + step) * NS + n] : p.xp_s[smn];
    float xg;
    const float* aA = p.aA_s + (size_t)step * (B * NS * G) + (size_t)smn * G;
    if (hist) {
      xg = aA[l];
    } else {
      float v = p.ellv_s[n * WS_ELL + l];
      int c = p.ellc_s[n * WS_ELL + l];
      float t = v * p.xp_s[b * NS + c];
#pragma unroll
      for (int m = 32; m; m >>= 1) t += __shfl_xor(t, m, 64);
      float acc = aA[l] + x0 * p.conv_w[l] + t * p.conv_w[DIN * G + l];
      xg = sigm_(acc);
      p.xg_s[(size_t)smn * G + l] = xg;
    }
    unsigned short hh, ll;
    split1(xg, hh, ll);
    size_t o = (size_t)smn * XCW;
    p.xsh[o + 28 + l] = hh; p.xsl[o + 28 + l] = ll;
    if (l < DIN) {
      float xv = (l == 0) ? x0
        : p.feat_s[(((size_t)b * T_ALL + step + 1) * NS + n) * DM + (l - 1)];
      split1(xv, hh, ll);
      p.xsh[o + l] = hh; p.xsl[o + l] = ll;
    }
  } else if (wid < B * NS + B * NC) {
    const int cm = wid - B * NS, b = cm >> 8, n = cm & 255;
    float x0 = hist ? p.c_x_hist[((size_t)b * TH + step) * NC + n] : p.xp_c[cm];
    float xg;
    const float* aA = p.aA_c + (size_t)step * (B * NC * G) + (size_t)cm * G;
    if (hist) {
      xg = aA[l];
    } else {
      float v = p.ellv_c[n * WS_ELL + l];
      int c = p.ellc_c[n * WS_ELL + l];
      float t = v * p.xp_c[b * NC + c];
#pragma unroll
      for (int m = 32; m; m >>= 1) t += __shfl_xor(t, m, 64);
      float acc = aA[l] + x0 * p.c_conv_w[l] + t * p.c_conv_w[DIN * G + l];
      xg = sigm_(acc);
      p.xg_c[(size_t)cm * G + l] = xg;
    }
    unsigned short hh, ll;
    split1(xg, hh, ll);
    size_t o = (size_t)cm * XCW;
    p.xch[o + 28 + l] = hh; p.xcl[o + 28 + l] = ll;
    if (l < DIN) {
      float xv = (l == 0) ? x0
        : p.feat_c[(((size_t)b * T_ALL + step + 1) * NC + n) * DM + (l - 1)];
      split1(xv, hh, ll);
      p.xch[o + l] = hh; p.xcl[o + l] = ll;
    }
  }
}

// ---------------- stepA (full, fallback path only) ----------------
__global__ __launch_bounds__(NTHR) void stepA_kernel(Params p, int step, int hist) {
  __shared__ float xa[AR][DIN];
  __shared__ float lx[AR][DIN];
  const int bid = blockIdx.x, tid = threadIdx.x;
  for (int q = tid; q < AR * DIN; q += NTHR) {
    int i = q / DIN, f = q % DIN;
    int sta = (i < AS);
    int b, n;
    const int* cc; const float* vv; int trip;
    if (sta) {
      int smn = bid * AS + i; b = smn >> 12; n = smn & 4095;
      cc = &p.ellc_s[n * WS_ELL]; vv = &p.ellv_s[n * WS_ELL];
      trip = (p.deg_s[n] + 7) & ~7;
    } else {
      b = bid >> 8; n = bid & 255;
      cc = &p.ellc_c[n * WS_ELL]; vv = &p.ellv_c[n * WS_ELL];
      trip = (p.deg_c[n] + 7) & ~7;
    }
    float xv = xval(p, sta, hist, step, b, n, f);
    xa[i][f] = xv;
    unsigned short hh, ll;
    split1(xv, hh, ll);
    if (sta) {
      size_t o = (size_t)(bid * AS + i) * XCW + f;
      p.xsh[o] = hh; p.xsl[o] = ll;
    } else {
      size_t o = (size_t)bid * XCW + f;
      p.xch[o] = hh; p.xcl[o] = ll;
    }
    float acc = 0.0f;
    for (int e = 0; e < trip; e += 8) {
      float xv8[8];
#pragma unroll
      for (int u = 0; u < 8; u++) xv8[u] = xval(p, sta, hist, step, b, cc[e + u], f);
#pragma unroll
      for (int u = 0; u < 8; u++) acc += vv[e + u] * xv8[u];
    }
    lx[i][f] = acc;
  }
  __syncthreads();
  for (int q = tid; q < AR * G; q += NTHR) {
    int i = q >> 6, g = q & 63;
    int sta = (i < AS);
    const float* W = sta ? p.conv_w : p.c_conv_w;
    float acc = (sta ? p.conv_b : p.c_conv_b)[g];
#pragma unroll 4
    for (int f = 0; f < DIN; f++)
      acc += xa[i][f] * W[f * G + g] + lx[i][f] * W[DIN * G + f * G + g];
    float s = sigm_(acc);
    unsigned short hh, ll;
    split1(s, hh, ll);
    if (sta) {
      p.xg_s[(size_t)(bid * AS + i) * G + g] = s;
      size_t o = (size_t)(bid * AS + i) * XCW + 28 + g;
      p.xsh[o] = hh; p.xsl[o] = ll;
    } else {
      p.xg_c[(size_t)bid * G + g] = s;
      size_t o = (size_t)bid * XCW + 28 + g;
      p.xch[o] = hh; p.xcl[o] = ll;
    }
  }
}

// ---------------- stepB: afc gather + fused MFMA GRU GEMM + epilogue ----------------
// grid: NBLK_B=1024; block b covers stations [b*32,+32) and cities [b*2,+2).
// fold=1 (hist steps 0..5, big path): epilogue also writes NEXT step's x/xg cols
// for this block's rows (from x_hist/feat/aA[step+1]) so stepA_lite is skipped.
__global__ __launch_bounds__(NTHR, 4) void stepB_kernel(Params p, int step, int hist,
                                                        int idx, int fold) {
  __shared__ float cityfc[4][CROWS];
  __shared__ float fcs[4][SROWS];
  const int bid = blockIdx.x, tid = threadIdx.x;
  unsigned short* xsh = p.xsh + (size_t)bid * SROWS * XCW;
  unsigned short* xsl = p.xsl + (size_t)bid * SROWS * XCW;
  unsigned short* xch = p.xch + (size_t)bid * CROWS * XCW;
  unsigned short* xcl = p.xcl + (size_t)bid * CROWS * XCW;

  // B1 stations (deg~4): buf -> xcat cols 92..155
#pragma unroll
  for (int k = 0; k < (SROWS * G) / NTHR; k++) {
    int q = tid + k * NTHR;
    int i = q >> 6, g = q & 63;
    int smn = bid * SROWS + i; int b = smn >> 12; int r = smn & 4095;
    int dg = p.degf[r];
    const int* cc = &p.ellf[r * WF_ELL];
    size_t bb = (size_t)b * NC;
    float acc = 0.0f;
    int e = 0;
    for (; e + 4 <= dg; e += 4) {
      acc += p.xg_c[(bb + cc[e]) * G + g] + p.xg_c[(bb + cc[e + 1]) * G + g]
           + p.xg_c[(bb + cc[e + 2]) * G + g] + p.xg_c[(bb + cc[e + 3]) * G + g];
    }
    for (; e < dg; e++) acc += p.xg_c[(bb + cc[e]) * G + g];
    unsigned short hh, ll;
    split1(acc, hh, ll);
    xsh[(size_t)i * XCW + 92 + g] = hh;
    xsl[(size_t)i * XCW + 92 + g] = ll;
  }
  // B1 cities (deg~64-96): 4 threads per (i,g)
  {
    int g = (tid >> 2) & 63;
    int quar = tid & 3;
#pragma unroll
    for (int ci = 0; ci < CROWS; ci++) {
      int cm = bid * CROWS + ci; int b = cm >> 8; int r = cm & 255;
      int dg = p.degfT[r];
      const int* cc = &p.ellfT[r * WFT_ELL];
      int dq = (dg + 3) >> 2;
      int e0 = quar * dq;
      int e1 = e0 + dq; if (e1 > dg) e1 = dg; if (e0 > dg) e0 = dg;
      size_t bb = (size_t)b * NS;
      float acc = 0.0f;
      int e = e0;
      for (; e + 4 <= e1; e += 4) {
        acc += p.xg_s[(bb + cc[e]) * G + g] + p.xg_s[(bb + cc[e + 1]) * G + g]
             + p.xg_s[(bb + cc[e + 2]) * G + g] + p.xg_s[(bb + cc[e + 3]) * G + g];
      }
      for (; e < e1; e++) acc += p.xg_s[(bb + cc[e]) * G + g];
      acc += __shfl_down(acc, 2, 4);
      acc += __shfl_down(acc, 1, 4);
      if (quar == 0) {
        unsigned short hh, ll;
        split1(acc, hh, ll);
        xch[(size_t)ci * XCW + 92 + g] = hh;
        xcl[(size_t)ci * XCW + 92 + g] = ll;
      }
    }
  }
  __syncthreads();

  // B3: MFMA GEMM gates[32(+2) x 256] = xcat[34 x 224] @ Wcat2[224 x 256]
  const int l = tid & 63;
  const int wv = tid >> 6;
  f32x4 accS[8];   // [rt*4 + gate]
  f32x4 accC[4];
#pragma unroll
  for (int t = 0; t < 8; t++) { accS[t][0] = 0.f; accS[t][1] = 0.f; accS[t][2] = 0.f; accS[t][3] = 0.f; }
#pragma unroll
  for (int t = 0; t < 4; t++) { accC[t][0] = 0.f; accC[t][1] = 0.f; accC[t][2] = 0.f; accC[t][3] = 0.f; }
  const bf16x8* WSh = (const bf16x8*)p.wSh;
  const bf16x8* WSl = (const bf16x8*)p.wSl;
  const bf16x8* WCh = (const bf16x8*)p.wCh;
  const bf16x8* WCl = (const bf16x8*)p.wCl;

  for (int q = 0; q < KIT; q++) {
    int kc = q * 32 + ((l >> 4) << 3);
    bf16x8 aS0h = *(const bf16x8*)(xsh + (size_t)(l & 15) * XCW + kc);
    bf16x8 aS0l = *(const bf16x8*)(xsl + (size_t)(l & 15) * XCW + kc);
    bf16x8 aS1h = *(const bf16x8*)(xsh + (size_t)(16 + (l & 15)) * XCW + kc);
    bf16x8 aS1l = *(const bf16x8*)(xsl + (size_t)(16 + (l & 15)) * XCW + kc);
    bf16x8 aCh, aCl;
    if ((l & 15) < CROWS) {
      aCh = *(const bf16x8*)(xch + (size_t)(l & 15) * XCW + kc);
      aCl = *(const bf16x8*)(xcl + (size_t)(l & 15) * XCW + kc);
    } else {
#pragma unroll
      for (int j = 0; j < 8; j++) { aCh[j] = 0; aCl[j] = 0; }
    }
    int base = q * (NT * 64) + l;
#pragma unroll
    for (int tt = 0; tt < 4; tt++) {
      int toff = base + (wv + tt * 4) * 64;
      bf16x8 wh_ = WSh[toff];
      bf16x8 wl_ = WSl[toff];
      accS[tt]     = __builtin_amdgcn_mfma_f32_16x16x32_bf16(aS0h, wh_, accS[tt], 0, 0, 0);
      accS[tt]     = __builtin_amdgcn_mfma_f32_16x16x32_bf16(aS0l, wh_, accS[tt], 0, 0, 0);
      accS[tt]     = __builtin_amdgcn_mfma_f32_16x16x32_bf16(aS0h, wl_, accS[tt], 0, 0, 0);
      accS[4 + tt] = __builtin_amdgcn_mfma_f32_16x16x32_bf16(aS1h, wh_, accS[4 + tt], 0, 0, 0);
      accS[4 + tt] = __builtin_amdgcn_mfma_f32_16x16x32_bf16(aS1l, wh_, accS[4 + tt], 0, 0, 0);
      accS[4 + tt] = __builtin_amdgcn_mfma_f32_16x16x32_bf16(aS1h, wl_, accS[4 + tt], 0, 0, 0);
      bf16x8 ch_ = WCh[toff];
      bf16x8 cl_ = WCl[toff];
      accC[tt] = __builtin_amdgcn_mfma_f32_16x16x32_bf16(aCh, ch_, accC[tt], 0, 0, 0);
      accC[tt] = __builtin_amdgcn_mfma_f32_16x16x32_bf16(aCl, ch_, accC[tt], 0, 0, 0);
      accC[tt] = __builtin_amdgcn_mfma_f32_16x16x32_bf16(aCh, cl_, accC[tt], 0, 0, 0);
    }
  }
  __syncthreads();   // all A-frag reads done before xcat cols are overwritten

  const int pred = !hist;
  const int t_out = step - (TH - 1);
  const int j = wv * 16 + (l & 15);
  const int upd = ((idx & ((1 << wv) - 1)) == 0);
  float fcacc[8];
  {
    float fwj = p.fc_w[j];
#pragma unroll
    for (int rt = 0; rt < 2; rt++) {
#pragma unroll
      for (int r = 0; r < 4; r++) {
        int row = rt * 16 + ((l >> 4) << 2) + r;
        float rr = sigm_(accS[rt * 4 + 0][r]);
        float zz = sigm_(accS[rt * 4 + 1][r]);
        float nn = tanhf(accS[rt * 4 + 2][r] + rr * accS[rt * 4 + 3][r]);
        size_t o = (size_t)row * XCW + 156 + j;
        float ho = bf16tof(xsh[o]) + bf16tof(xsl[o]);
        float hn = upd ? ((1.0f - zz) * nn + zz * ho) : ho;
        unsigned short hh, ll;
        split1(hn, hh, ll);
        xsh[o] = hh; xsl[o] = ll;
        fcacc[rt * 4 + r] = fwj * hn;
      }
    }
  }
  float cfc[CROWS] = {0.f, 0.f};
  if ((l >> 4) == 0) {
    float fwj = p.c_fc_w[j];
#pragma unroll
    for (int r = 0; r < CROWS; r++) {
      float rr = sigm_(accC[0][r]);
      float zz = sigm_(accC[1][r]);
      float nn = tanhf(accC[2][r] + rr * accC[3][r]);
      size_t o = (size_t)r * XCW + 156 + j;
      float ho = bf16tof(xch[o]) + bf16tof(xcl[o]);
      float hn = upd ? ((1.0f - zz) * nn + zz * ho) : ho;
      unsigned short hh, ll;
      split1(hn, hh, ll);
      xch[o] = hh; xcl[o] = ll;
      cfc[r] = fwj * hn;
    }
  }
  if (pred) {
#pragma unroll
    for (int rt = 0; rt < 2; rt++) {
#pragma unroll
      for (int r = 0; r < 4; r++) {
        float v = fcacc[rt * 4 + r];
        v += __shfl_down(v, 8, 16);
        v += __shfl_down(v, 4, 16);
        v += __shfl_down(v, 2, 16);
        v += __shfl_down(v, 1, 16);
        if ((l & 15) == 0) fcs[wv][rt * 16 + ((l >> 4) << 2) + r] = v;
      }
    }
#pragma unroll
    for (int r = 0; r < CROWS; r++) {
      float v = cfc[r];
      v += __shfl_down(v, 8, 16);
      v += __shfl_down(v, 4, 16);
      v += __shfl_down(v, 2, 16);
      v += __shfl_down(v, 1, 16);
      if (l == 0) cityfc[wv][r] = v;
    }
    __syncthreads();
    if (tid < SROWS) {
      float y = fcs[0][tid] + fcs[1][tid] + fcs[2][tid] + fcs[3][tid] + p.fc_b[0];
      int smn = bid * SROWS + tid; int b = smn >> 12; int n = smn & 4095;
      p.out[((size_t)b * TP + t_out) * NS + n] = y;
      p.xp_s[smn] = y;
    }
    if (tid >= 64 && tid < 64 + CROWS) {
      int r = tid - 64;
      float y = cityfc[0][r] + cityfc[1][r] + cityfc[2][r] + cityfc[3][r] + p.c_fc_b[0];
      int cm = bid * CROWS + r; int b = cm >> 8; int n = cm & 255;
      p.out[(size_t)B * TP * NS + ((size_t)b * TP + t_out) * NC + n] = y;
      p.xp_c[cm] = y;
    }
  }
  // fold: write next hist step's x (cols 0..27) and xg (28..91) for our rows.
  if (fold) {
    const float* aAn_s = p.aA_s + (size_t)(step + 1) * (B * NS * G);
    const float* aAn_c = p.aA_c + (size_t)(step + 1) * (B * NC * G);
    for (int u = tid; u < SROWS * 92; u += NTHR) {
      int i = u / 92, c = u % 92;
      int smn = bid * SROWS + i; int b = smn >> 12; int n = smn & 4095;
      float v;
      if (c == 0)      v = p.x_hist[((size_t)b * TH + step + 1) * NS + n];
      else if (c < 28) v = p.feat_s[(((size_t)b * T_ALL + step + 2) * NS + n) * DM + (c - 1)];
      else             v = aAn_s[(size_t)smn * G + (c - 28)];
      unsigned short hh, ll;
      split1(v, hh, ll);
      xsh[(size_t)i * XCW + c] = hh;
      xsl[(size_t)i * XCW + c] = ll;
    }
    for (int u = tid; u < CROWS * 92; u += NTHR) {
      int i = u / 92, c = u % 92;
      int cm = bid * CROWS + i; int b = cm >> 8; int n = cm & 255;
      float v;
      if (c == 0)      v = p.c_x_hist[((size_t)b * TH + step + 1) * NC + n];
      else if (c < 28) v = p.feat_c[(((size_t)b * T_ALL + step + 2) * NC + n) * DM + (c - 1)];
      else             v = aAn_c[(size_t)cm * G + (c - 28)];
      unsigned short hh, ll;
      split1(v, hh, ll);
      xch[(size_t)i * XCW + c] = hh;
      xcl[(size_t)i * XCW + c] = ll;
    }
  }
}

// ---------------- prologue kernels ----------------
__global__ __launch_bounds__(NTHR) void build_kernel(Params p) {
  build_tables(p, blockIdx.x, threadIdx.x, gridDim.x);
}
__global__ __launch_bounds__(NTHR) void ellv_kernel(Params p) {
  ellv_fill(p, blockIdx.x * NTHR + threadIdx.x, gridDim.x * NTHR);
}

extern "C" void kernel_launch(void* const* d_in, const int* in_sizes, int n_in,
                              void* d_out, int out_size, void* d_ws, size_t ws_size,
                              hipStream_t stream) {
  Params p;
  p.x_hist   = (const float*)d_in[0];
  p.feat_s   = (const float*)d_in[1];
  p.c_x_hist = (const float*)d_in[2];
  p.feat_c   = (const float*)d_in[3];
  p.adj_s    = (const float*)d_in[4];
  p.adj_c    = (const float*)d_in[5];
  p.afc      = (const float*)d_in[6];
  p.conv_w   = (const float*)d_in[7];
  p.conv_b   = (const float*)d_in[8];
  p.c_conv_w = (const float*)d_in[9];
  p.c_conv_b = (const float*)d_in[10];
  p.gru_wi   = (const float*)d_in[11];
  p.gru_wh   = (const float*)d_in[12];
  p.gru_bi   = (const float*)d_in[13];
  p.gru_bh   = (const float*)d_in[14];
  p.c_gru_wi = (const float*)d_in[15];
  p.c_gru_wh = (const float*)d_in[16];
  p.c_gru_bi = (const float*)d_in[17];
  p.c_gru_bh = (const float*)d_in[18];
  p.fc_w     = (const float*)d_in[19];
  p.fc_b     = (const float*)d_in[20];
  p.c_fc_w   = (const float*)d_in[21];
  p.c_fc_b   = (const float*)d_in[22];
  p.c2s_w    = (const float*)d_in[23];
  p.c2s_b    = (const float*)d_in[24];
  p.s2c_w    = (const float*)d_in[25];
  p.s2c_b    = (const float*)d_in[26];

  char* wp = (char*)d_ws;
  auto alloc = [&](size_t bytes) -> char* {
    char* q = wp;
    wp += (bytes + 255) & ~(size_t)255;
    return q;
  };
  p.deg_s  = (int*)alloc(NS * 4);
  p.dinv_s = (float*)alloc(NS * 4);
  p.ellc_s = (int*)alloc((size_t)NS * WS_ELL * 4);
  p.ellv_s = (float*)alloc((size_t)NS * WS_ELL * 4);
  p.deg_c  = (int*)alloc(NC * 4);
  p.dinv_c = (float*)alloc(NC * 4);
  p.ellc_c = (int*)alloc((size_t)NC * WS_ELL * 4);
  p.ellv_c = (float*)alloc((size_t)NC * WS_ELL * 4);
  p.degf   = (int*)alloc(NS * 4);
  p.ellf   = (int*)alloc((size_t)NS * WF_ELL * 4);
  p.degfT  = (int*)alloc(NC * 4);
  p.ellfT  = (int*)alloc((size_t)NC * WFT_ELL * 4);
  p.xg_s   = (float*)alloc((size_t)B * NS * G * 4);
  p.xg_c   = (float*)alloc((size_t)B * NC * G * 4);
  p.xp_s   = (float*)alloc((size_t)B * NS * 4);
  p.xp_c   = (float*)alloc((size_t)B * NC * 4);
  p.xsh    = (unsigned short*)alloc((size_t)B * NS * XCW * 2);
  p.xsl    = (unsigned short*)alloc((size_t)B * NS * XCW * 2);
  p.xch    = (unsigned short*)alloc((size_t)B * NC * XCW * 2);
  p.xcl    = (unsigned short*)alloc((size_t)B * NC * XCW * 2);
  p.wSh    = (unsigned short*)alloc((size_t)WFRAG * 2);
  p.wSl    = (unsigned short*)alloc((size_t)WFRAG * 2);
  p.wCh    = (unsigned short*)alloc((size_t)WFRAG * 2);
  p.wCl    = (unsigned short*)alloc((size_t)WFRAG * 2);
  p.wcvSh  = (unsigned short*)alloc((size_t)CVFRAG * 2);
  p.wcvSl  = (unsigned short*)alloc((size_t)CVFRAG * 2);
  p.wcvCh  = (unsigned short*)alloc((size_t)CVFRAG * 2);
  p.wcvCl  = (unsigned short*)alloc((size_t)CVFRAG * 2);
  p.aA_s   = (float*)alloc((size_t)NSTEP * B * NS * G * 4);   // 260 MB
  p.aA_c   = (float*)alloc((size_t)NSTEP * B * NC * G * 4);   // 16 MB
  p.out    = (float*)d_out;

  const bool big = ((size_t)(wp - (char*)d_ws) <= ws_size);

  build_kernel<<<2048, NTHR, 0, stream>>>(p);
  ellv_kernel<<<2048, NTHR, 0, stream>>>(p);
  if (big) {
    precompA2_kernel<<<NSTEP * 2048, NTHR, 0, stream>>>(p);
    for (int step = 0; step < NSTEP; step++) {
      int hist = (step < TH - 1) ? 1 : 0;
      // steps 1..TH-2 have x/xg pre-written by stepB(step-1)'s fold epilogue
      bool skipA = (step >= 1 && step <= TH - 2);
      if (!skipA)
        stepA_lite_kernel<<<(B * NS + B * NC) / 4, NTHR, 0, stream>>>(p, step, hist);
      Params pb = p;
      if (hist) {
        pb.xg_s = p.aA_s + (size_t)step * (B * NS * G);
        pb.xg_c = p.aA_c + (size_t)step * (B * NC * G);
      }
      int fold = (hist && step + 1 <= TH - 2) ? 1 : 0;
      stepB_kernel<<<NBLK_B, NTHR, 0, stream>>>(pb, step, hist, step + 1, fold);
    }
  } else {
    for (int step = 0; step < NSTEP; step++) {
      int hist = (step < TH - 1) ? 1 : 0;
      stepA_kernel<<<NBLK_A, NTHR, 0, stream>>>(p, step, hist);
      stepB_kernel<<<NBLK_B, NTHR, 0, stream>>>(p, step, hist, step + 1, 0);
    }
  }
}

// Round 10
// 2892.373 us; speedup vs baseline: 1.0473x; 1.0473x over previous
//
#include <hip/hip_runtime.h>
#include <math.h>

typedef short bf16x8 __attribute__((ext_vector_type(8)));
typedef float f32x4 __attribute__((ext_vector_type(4)));

#define B 8
#define NS 4096
#define NC 256
#define TH 8
#define TP 24
#define T_ALL 32
#define DIN 28
#define DM 27
#define G 64
#define H 64
#define NG3 192
#define NSTEP 31

#define NTHR 256
// phase-B geometry: 1024 blocks, 4 blocks/CU (verified round-5/8)
#define NBLK_B 1024
#define SROWS 32          // station rows per B-block
#define CROWS 2           // city rows per B-block
// phase-A geometry (precomp / fallback grid)
#define NBLK_A 2048
#define AS 16             // station rows per A-block
#define AR 17             // +1 city row

// xcat K layout: 0..27 x | 28..91 own_xg | 92..155 buf | 156..219 h | 220 bias | 221..223 pad
#define XCW 224
#define KIT 7             // K-iters of 32
#define NT 16             // N tiles (256 gate cols)
#define WFRAG (KIT*NT*64*8)   // 57344 bf16 per weight array
#define CVFRAG (2*4*64*8)     // 4096 bf16 per conv-weight array (K=64, N=64)

#define WS_ELL 64
#define WF_ELL 32
#define WFT_ELL 128

struct Params {
  const float *x_hist, *feat_s, *c_x_hist, *feat_c, *adj_s, *adj_c, *afc;
  const float *conv_w, *conv_b, *c_conv_w, *c_conv_b;
  const float *gru_wi, *gru_wh, *gru_bi, *gru_bh;
  const float *c_gru_wi, *c_gru_wh, *c_gru_bi, *c_gru_bh;
  const float *fc_w, *fc_b, *c_fc_w, *c_fc_b;
  const float *c2s_w, *c2s_b, *s2c_w, *s2c_b;
  int *deg_s, *ellc_s; float *ellv_s, *dinv_s;
  int *deg_c, *ellc_c; float *ellv_c, *dinv_c;
  int *degf, *ellf;
  int *degfT, *ellfT;
  float *xg_s, *xg_c, *xp_s, *xp_c;
  unsigned short *xsh, *xsl;         // [B*NS][XCW] bf16 hi/lo (pre-split A matrix)
  unsigned short *xch, *xcl;         // [B*NC][XCW] bf16 hi/lo
  unsigned short *wSh, *wSl, *wCh, *wCl;  // fragment-ordered Wcat2 bf16 hi/lo
  unsigned short *wcvSh, *wcvSl, *wcvCh, *wcvCl; // conv-weight fragments [K=64 x N=64]
  float *aA_s, *aA_c;                // [NSTEP][nodes][G]: hist->xg, pred->conv partial
  float *out;
};

__device__ __forceinline__ float sigm_(float x) { return 1.0f / (1.0f + expf(-x)); }

__device__ __forceinline__ unsigned short bf16rn(float f) {
  unsigned u = __float_as_uint(f);
  u += 0x7fffu + ((u >> 16) & 1u);
  return (unsigned short)(u >> 16);
}
__device__ __forceinline__ float bf16tof(unsigned short h) {
  return __uint_as_float(((unsigned)h) << 16);
}
__device__ __forceinline__ void split1(float f, unsigned short& hi, unsigned short& lo) {
  hi = bf16rn(f);
  lo = bf16rn(f - bf16tof(hi));
}

// LDS swizzle for precompA2 (kept from round 8: conflicts 1.7e7 -> 2.3e6)
__device__ __forceinline__ int sidx(int i, int c) {
  return i * 64 + (c ^ ((i & 7) << 3));
}

// Original Wcat[k][c], k in 0..156: rows 0..91 = wi, 92..155 = wh, 156 = bias.
// cols 0..127 = r,z (x+h fused); 128..191 = xn (wi only); 192..255 = hc (wh only).
__device__ float wcat_val(int k, int c, const float* wi, const float* wh,
                          const float* bi, const float* bh) {
  if (k < 92)  { return (c < 192) ? wi[k * NG3 + c] : 0.0f; }
  if (k < 156) {
    int kk = k - 92;
    if (c < 128) return wh[kk * NG3 + c];
    if (c < 192) return 0.0f;
    return wh[kk * NG3 + (c - 64)];
  }
  if (k == 156) {
    if (c < 128) return bi[c] + bh[c];
    if (c < 192) return bi[c];
    return bh[c - 64];
  }
  return 0.0f;
}

// Extended Wcat2[k][c], k in 0..223, folding the fuse stage.
// Zero structure (exploited in stepB): cols 128..191 have k 156..219 == 0
// (kiter 5 zero); cols 192..255 have k 0..155 == 0 (kiters 0..3 zero).
__device__ float wcat2_val(int k, int c, const float* wi, const float* wh,
                           const float* bi, const float* bh,
                           const float* wm, const float* bm) {
  if (k < 92) return wcat_val(k, c, wi, wh, bi, bh);
  if (k < 156) {
    int f = k - 92;
    float s = 0.0f;
    for (int g = 0; g < G; g++)
      s += wm[f * G + g] * wcat_val(28 + g, c, wi, wh, bi, bh);
    return s;
  }
  if (k < 220) return wcat_val(92 + (k - 156), c, wi, wh, bi, bh);
  if (k == 220) {
    float s = wcat_val(156, c, wi, wh, bi, bh);
    for (int g = 0; g < G; g++)
      s += bm[g] * wcat_val(28 + g, c, wi, wh, bi, bh);
    return s;
  }
  return 0.0f;
}

// x channel f of node n at global step (fallback stepA only).
__device__ __forceinline__ float xval(const Params& p, int sta, int hist, int step,
                                      int b, int n, int f) {
  if (f == 0) {
    if (hist) return sta ? p.x_hist[((size_t)b * TH + step) * NS + n]
                         : p.c_x_hist[((size_t)b * TH + step) * NC + n];
    return sta ? p.xp_s[b * NS + n] : p.xp_c[b * NC + n];
  }
  int tf = step + 1;
  return sta ? p.feat_s[(((size_t)b * T_ALL + tf) * NS + n) * DM + (f - 1)]
             : p.feat_c[(((size_t)b * T_ALL + tf) * NC + n) * DM + (f - 1)];
}

// ---------------- P0: ELL tables + weight fragment prep + xcat init ----------------
__device__ void build_tables(const Params& p, int bid, int tid, int nblk) {
  const int lane = tid & 63;
  const int gw = bid * 4 + (tid >> 6);
  const int nw = nblk * 4;

  for (int r = gw; r < NS; r += nw) {
    int base = 0;
    for (int n0 = 0; n0 < NS; n0 += 64) {
      int n = n0 + lane;
      float v = p.adj_s[(size_t)r * NS + n];
      bool fl = (v != 0.0f) && (n != r);
      unsigned long long m = __ballot(fl);
      if (fl) {
        int pos = base + (int)__popcll(m & ((1ull << lane) - 1ull));
        if (pos < WS_ELL) p.ellc_s[r * WS_ELL + pos] = n;
      }
      base += (int)__popcll(m);
    }
    int deg = base < WS_ELL ? base : WS_ELL;
    for (int s = deg + lane; s < WS_ELL; s += 64) p.ellc_s[r * WS_ELL + s] = 0;
    if (lane == 0) {
      p.deg_s[r] = deg;
      p.dinv_s[r] = base > 0 ? 1.0f / sqrtf((float)base) : 0.0f;
    }
  }
  for (int r = gw; r < NS; r += nw) {
    int base = 0;
    for (int n0 = 0; n0 < NC; n0 += 64) {
      int n = n0 + lane;
      bool fl = p.afc[(size_t)r * NC + n] != 0.0f;
      unsigned long long m = __ballot(fl);
      if (fl) {
        int pos = base + (int)__popcll(m & ((1ull << lane) - 1ull));
        if (pos < WF_ELL) p.ellf[r * WF_ELL + pos] = n;
      }
      base += (int)__popcll(m);
    }
    int deg = base < WF_ELL ? base : WF_ELL;
    for (int s = deg + lane; s < WF_ELL; s += 64) p.ellf[r * WF_ELL + s] = 0;
    if (lane == 0) p.degf[r] = deg;
  }
  for (int r = gw; r < NC; r += nw) {
    int base = 0;
    for (int n0 = 0; n0 < NC; n0 += 64) {
      int n = n0 + lane;
      float v = p.adj_c[(size_t)r * NC + n];
      bool fl = (v != 0.0f) && (n != r);
      unsigned long long m = __ballot(fl);
      if (fl) {
        int pos = base + (int)__popcll(m & ((1ull << lane) - 1ull));
        if (pos < WS_ELL) p.ellc_c[r * WS_ELL + pos] = n;
      }
      base += (int)__popcll(m);
    }
    int deg = base < WS_ELL ? base : WS_ELL;
    for (int s = deg + lane; s < WS_ELL; s += 64) p.ellc_c[r * WS_ELL + s] = 0;
    if (lane == 0) {
      p.deg_c[r] = deg;
      p.dinv_c[r] = base > 0 ? 1.0f / sqrtf((float)base) : 0.0f;
    }
  }
  for (int r = gw; r < NC; r += nw) {
    int base = 0;
    for (int n0 = 0; n0 < NS; n0 += 64) {
      int n = n0 + lane;
      bool fl = p.afc[(size_t)n * NC + r] != 0.0f;
      unsigned long long m = __ballot(fl);
      if (fl) {
        int pos = base + (int)__popcll(m & ((1ull << lane) - 1ull));
        if (pos < WFT_ELL) p.ellfT[r * WFT_ELL + pos] = n;
      }
      base += (int)__popcll(m);
    }
    int deg = base < WFT_ELL ? base : WFT_ELL;
    for (int s = deg + lane; s < WFT_ELL; s += 64) p.ellfT[r * WFT_ELL + s] = 0;
    if (lane == 0) p.degfT[r] = deg;
  }

  const int gid = bid * NTHR + tid, ntot = nblk * NTHR;
  // xp holds x_prev for the first pred step (= x_hist[:, TH-1])
  for (int i = gid; i < B * NS; i += ntot)
    p.xp_s[i] = p.x_hist[((size_t)(i / NS) * TH + (TH - 1)) * NS + (i % NS)];
  for (int i = gid; i < B * NC; i += ntot)
    p.xp_c[i] = p.c_x_hist[((size_t)(i / NC) * TH + (TH - 1)) * NC + (i % NC)];

  // GRU weight fragments: u -> (kiter q, tile t, lane l, j); k = q*32 + (l>>4)*8 + j
  for (int u = gid; u < WFRAG; u += ntot) {
    int j = u & 7, l = (u >> 3) & 63, t = (u >> 9) & 15, q = u >> 13;
    int k = q * 32 + ((l >> 4) << 3) + j;
    int c = t * 16 + (l & 15);
    float ws = wcat2_val(k, c, p.gru_wi, p.gru_wh, p.gru_bi, p.gru_bh, p.c2s_w, p.c2s_b);
    unsigned short hh, ll;
    split1(ws, hh, ll);
    p.wSh[u] = hh; p.wSl[u] = ll;
    float wc = wcat2_val(k, c, p.c_gru_wi, p.c_gru_wh, p.c_gru_bi, p.c_gru_bh, p.s2c_w, p.s2c_b);
    split1(wc, hh, ll);
    p.wCh[u] = hh; p.wCl[u] = ll;
  }
  // conv weight fragments (K=64: 0..27 = W0, 28..55 = W1, 56..63 = 0; N=64).
  for (int u = gid; u < CVFRAG; u += ntot) {
    int j = u & 7, l = (u >> 3) & 63, t = (u >> 9) & 3, q = u >> 11;
    int k = q * 32 + ((l >> 4) << 3) + j;
    int c = t * 16 + (l & 15);
    float vs = (k < 56) ? p.conv_w[k * G + c] : 0.0f;
    unsigned short hh, ll;
    split1(vs, hh, ll);
    p.wcvSh[u] = hh; p.wcvSl[u] = ll;
    float vc = (k < 56) ? p.c_conv_w[k * G + c] : 0.0f;
    split1(vc, hh, ll);
    p.wcvCh[u] = hh; p.wcvCl[u] = ll;
  }
  // xcat init: zeros (h state!), col 220 = 1.0 (bias)
  for (int u = gid; u < B * NS * XCW; u += ntot) {
    p.xsh[u] = ((u % XCW) == 220) ? 0x3F80 : 0;
    p.xsl[u] = 0;
  }
  for (int u = gid; u < B * NC * XCW; u += ntot) {
    p.xch[u] = ((u % XCW) == 220) ? 0x3F80 : 0;
    p.xcl[u] = 0;
  }
}

__device__ void ellv_fill(const Params& p, int gid, int ntot) {
  for (int s = gid; s < NS * WS_ELL; s += ntot) {
    int r = s >> 6, k = s & (WS_ELL - 1);
    p.ellv_s[s] = (k < p.deg_s[r]) ? -p.dinv_s[r] * p.dinv_s[p.ellc_s[s]] : 0.0f;
  }
  for (int s = gid; s < NC * WS_ELL; s += ntot) {
    int r = s >> 6, k = s & (WS_ELL - 1);
    p.ellv_c[s] = (k < p.deg_c[r]) ? -p.dinv_c[r] * p.dinv_c[p.ellc_c[s]] : 0.0f;
  }
}

// ---------------- precompA2: step-static cheb gather + MFMA conv for ALL steps ----------------
// grid: NSTEP*2048; block = (step, 16 stations + 1 city). Round-8 verified config
// (8-wide gather, 91% occupancy, ~532 us; round-9's 16-wide widening regressed).
__global__ __launch_bounds__(NTHR) void precompA2_kernel(Params p) {
  __shared__ unsigned short lh[AR * 64];
  __shared__ unsigned short llo[AR * 64];
  const int bid = blockIdx.x & 2047;
  const int step = blockIdx.x >> 11;
  const int hist = (step < TH - 1) ? 1 : 0;
  const int tid = threadIdx.x;
  const int b = bid >> 8;              // uniform per block

  // zero K-pad cols 56..63
  for (int u = tid; u < AR * 8; u += NTHR) {
    lh[sidx(u >> 3, 56 + (u & 7))] = 0;
    llo[sidx(u >> 3, 56 + (u & 7))] = 0;
  }

  for (int q = tid; q < AR * DIN; q += NTHR) {
    int i = q / DIN, f = q % DIN;
    int sta = (i < AS);
    int n;
    const int* cc; const float* vv; int trip;
    if (sta) {
      n = (bid * AS + i) & 4095;
      cc = &p.ellc_s[n * WS_ELL]; vv = &p.ellv_s[n * WS_ELL];
      trip = (p.deg_s[n] + 7) & ~7;
    } else {
      n = bid & 255;
      cc = &p.ellc_c[n * WS_ELL]; vv = &p.ellv_c[n * WS_ELL];
      trip = (p.deg_c[n] + 7) & ~7;
    }
    float xv = 0.0f, acc = 0.0f;
    if (f == 0) {
      if (hist) {
        const float* bh = sta ? (p.x_hist + ((size_t)b * TH + step) * NS)
                              : (p.c_x_hist + ((size_t)b * TH + step) * NC);
        xv = bh[n];
        for (int e = 0; e < trip; e += 8) {
          float xv8[8];
#pragma unroll
          for (int u = 0; u < 8; u++) xv8[u] = bh[cc[e + u]];
#pragma unroll
          for (int u = 0; u < 8; u++) acc += vv[e + u] * xv8[u];
        }
      }
      // pred: xv = acc = 0 (f=0 terms added per step in stepA_lite)
    } else {
      const float* bf = sta
        ? (p.feat_s + ((size_t)(b * T_ALL + step + 1) * NS) * DM + (f - 1))
        : (p.feat_c + ((size_t)(b * T_ALL + step + 1) * NC) * DM + (f - 1));
      xv = bf[(size_t)n * DM];
      for (int e = 0; e < trip; e += 8) {
        float xv8[8];
#pragma unroll
        for (int u = 0; u < 8; u++) xv8[u] = bf[(size_t)cc[e + u] * DM];
#pragma unroll
        for (int u = 0; u < 8; u++) acc += vv[e + u] * xv8[u];
      }
    }
    unsigned short hh, ll;
    split1(xv, hh, ll);
    lh[sidx(i, f)] = hh; llo[sidx(i, f)] = ll;
    split1(acc, hh, ll);
    lh[sidx(i, 28 + f)] = hh; llo[sidx(i, 28 + f)] = ll;
  }
  __syncthreads();

  // MFMA conv: wave wv owns output cols [wv*16, wv*16+16).
  const int l = tid & 63;
  const int wv = tid >> 6;
  f32x4 a1; f32x4 a2;
  a1[0] = 0.f; a1[1] = 0.f; a1[2] = 0.f; a1[3] = 0.f;
  a2[0] = 0.f; a2[1] = 0.f; a2[2] = 0.f; a2[3] = 0.f;
  const bf16x8* WVSh = (const bf16x8*)p.wcvSh;
  const bf16x8* WVSl = (const bf16x8*)p.wcvSl;
  const bf16x8* WVCh = (const bf16x8*)p.wcvCh;
  const bf16x8* WVCl = (const bf16x8*)p.wcvCl;
#pragma unroll
  for (int q = 0; q < 2; q++) {
    int kc = q * 32 + ((l >> 4) << 3);
    bf16x8 xh = *(const bf16x8*)&lh[sidx(l & 15, kc)];
    bf16x8 xl = *(const bf16x8*)&llo[sidx(l & 15, kc)];
    bf16x8 ch_, cl_;
    if ((l & 15) == 0) {
      ch_ = *(const bf16x8*)&lh[sidx(AS, kc)];
      cl_ = *(const bf16x8*)&llo[sidx(AS, kc)];
    } else {
#pragma unroll
      for (int j = 0; j < 8; j++) { ch_[j] = 0; cl_[j] = 0; }
    }
    int u = (q * 4 + wv) * 64 + l;
    bf16x8 bh_ = WVSh[u];
    bf16x8 bl_ = WVSl[u];
    a1 = __builtin_amdgcn_mfma_f32_16x16x32_bf16(xh, bh_, a1, 0, 0, 0);
    a1 = __builtin_amdgcn_mfma_f32_16x16x32_bf16(xl, bh_, a1, 0, 0, 0);
    a1 = __builtin_amdgcn_mfma_f32_16x16x32_bf16(xh, bl_, a1, 0, 0, 0);
    bf16x8 gh_ = WVCh[u];
    bf16x8 gl_ = WVCl[u];
    a2 = __builtin_amdgcn_mfma_f32_16x16x32_bf16(ch_, gh_, a2, 0, 0, 0);
    a2 = __builtin_amdgcn_mfma_f32_16x16x32_bf16(cl_, gh_, a2, 0, 0, 0);
    a2 = __builtin_amdgcn_mfma_f32_16x16x32_bf16(ch_, gl_, a2, 0, 0, 0);
  }

  const int g = wv * 16 + (l & 15);
  float* dst_s = p.aA_s + (size_t)step * (B * NS * G);
  float* dst_c = p.aA_c + (size_t)step * (B * NC * G);
  float bias = p.conv_b[g];
#pragma unroll
  for (int r = 0; r < 4; r++) {
    int row = ((l >> 4) << 2) + r;     // 0..15
    float v = a1[r] + bias;
    if (hist) v = sigm_(v);
    dst_s[(size_t)(bid * AS + row) * G + g] = v;
  }
  if ((l >> 4) == 0) {                  // city: C row 0 lives in lanes 0..15, reg 0
    float v = a2[0] + p.c_conv_b[g];
    if (hist) v = sigm_(v);
    dst_c[(size_t)bid * G + g] = v;
  }
}

// ---------------- stepA_lite: per-step dynamic completion ----------------
__global__ __launch_bounds__(NTHR) void stepA_lite_kernel(Params p, int step, int hist) {
  const int tid = threadIdx.x;
  const int l = tid & 63, wv = tid >> 6;
  const int wid = blockIdx.x * 4 + wv;
  if (wid < B * NS) {
    const int smn = wid, b = smn >> 12, n = smn & 4095;
    float x0 = hist ? p.x_hist[((size_t)b * TH + step) * NS + n] : p.xp_s[smn];
    float xg;
    const float* aA = p.aA_s + (size_t)step * (B * NS * G) + (size_t)smn * G;
    if (hist) {
      xg = aA[l];
    } else {
      float v = p.ellv_s[n * WS_ELL + l];
      int c = p.ellc_s[n * WS_ELL + l];
      float t = v * p.xp_s[b * NS + c];
#pragma unroll
      for (int m = 32; m; m >>= 1) t += __shfl_xor(t, m, 64);
      float acc = aA[l] + x0 * p.conv_w[l] + t * p.conv_w[DIN * G + l];
      xg = sigm_(acc);
      p.xg_s[(size_t)smn * G + l] = xg;
    }
    unsigned short hh, ll;
    split1(xg, hh, ll);
    size_t o = (size_t)smn * XCW;
    p.xsh[o + 28 + l] = hh; p.xsl[o + 28 + l] = ll;
    if (l < DIN) {
      float xv = (l == 0) ? x0
        : p.feat_s[(((size_t)b * T_ALL + step + 1) * NS + n) * DM + (l - 1)];
      split1(xv, hh, ll);
      p.xsh[o + l] = hh; p.xsl[o + l] = ll;
    }
  } else if (wid < B * NS + B * NC) {
    const int cm = wid - B * NS, b = cm >> 8, n = cm & 255;
    float x0 = hist ? p.c_x_hist[((size_t)b * TH + step) * NC + n] : p.xp_c[cm];
    float xg;
    const float* aA = p.aA_c + (size_t)step * (B * NC * G) + (size_t)cm * G;
    if (hist) {
      xg = aA[l];
    } else {
      float v = p.ellv_c[n * WS_ELL + l];
      int c = p.ellc_c[n * WS_ELL + l];
      float t = v * p.xp_c[b * NC + c];
#pragma unroll
      for (int m = 32; m; m >>= 1) t += __shfl_xor(t, m, 64);
      float acc = aA[l] + x0 * p.c_conv_w[l] + t * p.c_conv_w[DIN * G + l];
      xg = sigm_(acc);
      p.xg_c[(size_t)cm * G + l] = xg;
    }
    unsigned short hh, ll;
    split1(xg, hh, ll);
    size_t o = (size_t)cm * XCW;
    p.xch[o + 28 + l] = hh; p.xcl[o + 28 + l] = ll;
    if (l < DIN) {
      float xv = (l == 0) ? x0
        : p.feat_c[(((size_t)b * T_ALL + step + 1) * NC + n) * DM + (l - 1)];
      split1(xv, hh, ll);
      p.xch[o + l] = hh; p.xcl[o + l] = ll;
    }
  }
}

// ---------------- stepA (full, fallback path only) ----------------
__global__ __launch_bounds__(NTHR) void stepA_kernel(Params p, int step, int hist) {
  __shared__ float xa[AR][DIN];
  __shared__ float lx[AR][DIN];
  const int bid = blockIdx.x, tid = threadIdx.x;
  for (int q = tid; q < AR * DIN; q += NTHR) {
    int i = q / DIN, f = q % DIN;
    int sta = (i < AS);
    int b, n;
    const int* cc; const float* vv; int trip;
    if (sta) {
      int smn = bid * AS + i; b = smn >> 12; n = smn & 4095;
      cc = &p.ellc_s[n * WS_ELL]; vv = &p.ellv_s[n * WS_ELL];
      trip = (p.deg_s[n] + 7) & ~7;
    } else {
      b = bid >> 8; n = bid & 255;
      cc = &p.ellc_c[n * WS_ELL]; vv = &p.ellv_c[n * WS_ELL];
      trip = (p.deg_c[n] + 7) & ~7;
    }
    float xv = xval(p, sta, hist, step, b, n, f);
    xa[i][f] = xv;
    unsigned short hh, ll;
    split1(xv, hh, ll);
    if (sta) {
      size_t o = (size_t)(bid * AS + i) * XCW + f;
      p.xsh[o] = hh; p.xsl[o] = ll;
    } else {
      size_t o = (size_t)bid * XCW + f;
      p.xch[o] = hh; p.xcl[o] = ll;
    }
    float acc = 0.0f;
    for (int e = 0; e < trip; e += 8) {
      float xv8[8];
#pragma unroll
      for (int u = 0; u < 8; u++) xv8[u] = xval(p, sta, hist, step, b, cc[e + u], f);
#pragma unroll
      for (int u = 0; u < 8; u++) acc += vv[e + u] * xv8[u];
    }
    lx[i][f] = acc;
  }
  __syncthreads();
  for (int q = tid; q < AR * G; q += NTHR) {
    int i = q >> 6, g = q & 63;
    int sta = (i < AS);
    const float* W = sta ? p.conv_w : p.c_conv_w;
    float acc = (sta ? p.conv_b : p.c_conv_b)[g];
#pragma unroll 4
    for (int f = 0; f < DIN; f++)
      acc += xa[i][f] * W[f * G + g] + lx[i][f] * W[DIN * G + f * G + g];
    float s = sigm_(acc);
    unsigned short hh, ll;
    split1(s, hh, ll);
    if (sta) {
      p.xg_s[(size_t)(bid * AS + i) * G + g] = s;
      size_t o = (size_t)(bid * AS + i) * XCW + 28 + g;
      p.xsh[o] = hh; p.xsl[o] = ll;
    } else {
      p.xg_c[(size_t)bid * G + g] = s;
      size_t o = (size_t)bid * XCW + 28 + g;
      p.xch[o] = hh; p.xcl[o] = ll;
    }
  }
}

// ---------------- stepB: afc gather + fused MFMA GRU GEMM + epilogue ----------------
// grid: NBLK_B=1024 blocks; block b covers stations [b*32,+32) and cities [b*2,+2).
// B3 exploits Wcat2's structural zeros: tile tt=2 (xn cols) skips kiter 5;
// tile tt=3 (hc cols) skips kiters 0..3. Bit-identical results, -18% MFMA+weight loads.
__global__ __launch_bounds__(NTHR, 4) void stepB_kernel(Params p, int step, int hist, int idx) {
  __shared__ float cityfc[4][CROWS];
  __shared__ float fcs[4][SROWS];
  const int bid = blockIdx.x, tid = threadIdx.x;
  unsigned short* xsh = p.xsh + (size_t)bid * SROWS * XCW;
  unsigned short* xsl = p.xsl + (size_t)bid * SROWS * XCW;
  unsigned short* xch = p.xch + (size_t)bid * CROWS * XCW;
  unsigned short* xcl = p.xcl + (size_t)bid * CROWS * XCW;

  // B1 stations (deg~4): buf -> xcat cols 92..155
#pragma unroll
  for (int k = 0; k < (SROWS * G) / NTHR; k++) {
    int q = tid + k * NTHR;
    int i = q >> 6, g = q & 63;
    int smn = bid * SROWS + i; int b = smn >> 12; int r = smn & 4095;
    int dg = p.degf[r];
    const int* cc = &p.ellf[r * WF_ELL];
    size_t bb = (size_t)b * NC;
    float acc = 0.0f;
    int e = 0;
    for (; e + 4 <= dg; e += 4) {
      acc += p.xg_c[(bb + cc[e]) * G + g] + p.xg_c[(bb + cc[e + 1]) * G + g]
           + p.xg_c[(bb + cc[e + 2]) * G + g] + p.xg_c[(bb + cc[e + 3]) * G + g];
    }
    for (; e < dg; e++) acc += p.xg_c[(bb + cc[e]) * G + g];
    unsigned short hh, ll;
    split1(acc, hh, ll);
    xsh[(size_t)i * XCW + 92 + g] = hh;
    xsl[(size_t)i * XCW + 92 + g] = ll;
  }
  // B1 cities (deg~64-96): 4 threads per (i,g)
  {
    int g = (tid >> 2) & 63;
    int quar = tid & 3;
#pragma unroll
    for (int ci = 0; ci < CROWS; ci++) {
      int cm = bid * CROWS + ci; int b = cm >> 8; int r = cm & 255;
      int dg = p.degfT[r];
      const int* cc = &p.ellfT[r * WFT_ELL];
      int dq = (dg + 3) >> 2;
      int e0 = quar * dq;
      int e1 = e0 + dq; if (e1 > dg) e1 = dg; if (e0 > dg) e0 = dg;
      size_t bb = (size_t)b * NS;
      float acc = 0.0f;
      int e = e0;
      for (; e + 4 <= e1; e += 4) {
        acc += p.xg_s[(bb + cc[e]) * G + g] + p.xg_s[(bb + cc[e + 1]) * G + g]
             + p.xg_s[(bb + cc[e + 2]) * G + g] + p.xg_s[(bb + cc[e + 3]) * G + g];
      }
      for (; e < e1; e++) acc += p.xg_s[(bb + cc[e]) * G + g];
      acc += __shfl_down(acc, 2, 4);
      acc += __shfl_down(acc, 1, 4);
      if (quar == 0) {
        unsigned short hh, ll;
        split1(acc, hh, ll);
        xch[(size_t)ci * XCW + 92 + g] = hh;
        xcl[(size_t)ci * XCW + 92 + g] = ll;
      }
    }
  }
  __syncthreads();

  // B3: MFMA GEMM gates[32(+2) x 256] = xcat[34 x 224] @ Wcat2[224 x 256]
  const int l = tid & 63;
  const int wv = tid >> 6;
  f32x4 accS[8];   // [rt*4 + gate]
  f32x4 accC[4];
#pragma unroll
  for (int t = 0; t < 8; t++) { accS[t][0] = 0.f; accS[t][1] = 0.f; accS[t][2] = 0.f; accS[t][3] = 0.f; }
#pragma unroll
  for (int t = 0; t < 4; t++) { accC[t][0] = 0.f; accC[t][1] = 0.f; accC[t][2] = 0.f; accC[t][3] = 0.f; }
  const bf16x8* WSh = (const bf16x8*)p.wSh;
  const bf16x8* WSl = (const bf16x8*)p.wSl;
  const bf16x8* WCh = (const bf16x8*)p.wCh;
  const bf16x8* WCl = (const bf16x8*)p.wCl;

#pragma unroll
  for (int q = 0; q < KIT; q++) {
    int kc = q * 32 + ((l >> 4) << 3);
    bf16x8 aS0h = *(const bf16x8*)(xsh + (size_t)(l & 15) * XCW + kc);
    bf16x8 aS0l = *(const bf16x8*)(xsl + (size_t)(l & 15) * XCW + kc);
    bf16x8 aS1h = *(const bf16x8*)(xsh + (size_t)(16 + (l & 15)) * XCW + kc);
    bf16x8 aS1l = *(const bf16x8*)(xsl + (size_t)(16 + (l & 15)) * XCW + kc);
    bf16x8 aCh, aCl;
    if ((l & 15) < CROWS) {
      aCh = *(const bf16x8*)(xch + (size_t)(l & 15) * XCW + kc);
      aCl = *(const bf16x8*)(xcl + (size_t)(l & 15) * XCW + kc);
    } else {
#pragma unroll
      for (int j = 0; j < 8; j++) { aCh[j] = 0; aCl[j] = 0; }
    }
    int base = q * (NT * 64) + l;
#pragma unroll
    for (int tt = 0; tt < 4; tt++) {
      // structural-zero skip: tt=2 (xn) has zero weights at kiter 5;
      // tt=3 (hc) has zero weights at kiters 0..3.
      if (tt == 2 && q == 5) continue;
      if (tt == 3 && q < 4) continue;
      int toff = base + (wv + tt * 4) * 64;
      bf16x8 wh_ = WSh[toff];
      bf16x8 wl_ = WSl[toff];
      accS[tt]     = __builtin_amdgcn_mfma_f32_16x16x32_bf16(aS0h, wh_, accS[tt], 0, 0, 0);
      accS[tt]     = __builtin_amdgcn_mfma_f32_16x16x32_bf16(aS0l, wh_, accS[tt], 0, 0, 0);
      accS[tt]     = __builtin_amdgcn_mfma_f32_16x16x32_bf16(aS0h, wl_, accS[tt], 0, 0, 0);
      accS[4 + tt] = __builtin_amdgcn_mfma_f32_16x16x32_bf16(aS1h, wh_, accS[4 + tt], 0, 0, 0);
      accS[4 + tt] = __builtin_amdgcn_mfma_f32_16x16x32_bf16(aS1l, wh_, accS[4 + tt], 0, 0, 0);
      accS[4 + tt] = __builtin_amdgcn_mfma_f32_16x16x32_bf16(aS1h, wl_, accS[4 + tt], 0, 0, 0);
      bf16x8 ch_ = WCh[toff];
      bf16x8 cl_ = WCl[toff];
      accC[tt] = __builtin_amdgcn_mfma_f32_16x16x32_bf16(aCh, ch_, accC[tt], 0, 0, 0);
      accC[tt] = __builtin_amdgcn_mfma_f32_16x16x32_bf16(aCl, ch_, accC[tt], 0, 0, 0);
      accC[tt] = __builtin_amdgcn_mfma_f32_16x16x32_bf16(aCh, cl_, accC[tt], 0, 0, 0);
    }
  }
  __syncthreads();   // all A-frag reads done before xcat cols are overwritten

  const int pred = !hist;
  const int t_out = step - (TH - 1);
  const int j = wv * 16 + (l & 15);
  const int upd = ((idx & ((1 << wv) - 1)) == 0);
  float fcacc[8];
  {
    float fwj = p.fc_w[j];
#pragma unroll
    for (int rt = 0; rt < 2; rt++) {
#pragma unroll
      for (int r = 0; r < 4; r++) {
        int row = rt * 16 + ((l >> 4) << 2) + r;
        float rr = sigm_(accS[rt * 4 + 0][r]);
        float zz = sigm_(accS[rt * 4 + 1][r]);
        float nn = tanhf(accS[rt * 4 + 2][r] + rr * accS[rt * 4 + 3][r]);
        size_t o = (size_t)row * XCW + 156 + j;
        float ho = bf16tof(xsh[o]) + bf16tof(xsl[o]);
        float hn = upd ? ((1.0f - zz) * nn + zz * ho) : ho;
        unsigned short hh, ll;
        split1(hn, hh, ll);
        xsh[o] = hh; xsl[o] = ll;
        fcacc[rt * 4 + r] = fwj * hn;
      }
    }
  }
  float cfc[CROWS] = {0.f, 0.f};
  if ((l >> 4) == 0) {
    float fwj = p.c_fc_w[j];
#pragma unroll
    for (int r = 0; r < CROWS; r++) {
      float rr = sigm_(accC[0][r]);
      float zz = sigm_(accC[1][r]);
      float nn = tanhf(accC[2][r] + rr * accC[3][r]);
      size_t o = (size_t)r * XCW + 156 + j;
      float ho = bf16tof(xch[o]) + bf16tof(xcl[o]);
      float hn = upd ? ((1.0f - zz) * nn + zz * ho) : ho;
      unsigned short hh, ll;
      split1(hn, hh, ll);
      xch[o] = hh; xcl[o] = ll;
      cfc[r] = fwj * hn;
    }
  }
  if (pred) {
#pragma unroll
    for (int rt = 0; rt < 2; rt++) {
#pragma unroll
      for (int r = 0; r < 4; r++) {
        float v = fcacc[rt * 4 + r];
        v += __shfl_down(v, 8, 16);
        v += __shfl_down(v, 4, 16);
        v += __shfl_down(v, 2, 16);
        v += __shfl_down(v, 1, 16);
        if ((l & 15) == 0) fcs[wv][rt * 16 + ((l >> 4) << 2) + r] = v;
      }
    }
#pragma unroll
    for (int r = 0; r < CROWS; r++) {
      float v = cfc[r];
      v += __shfl_down(v, 8, 16);
      v += __shfl_down(v, 4, 16);
      v += __shfl_down(v, 2, 16);
      v += __shfl_down(v, 1, 16);
      if (l == 0) cityfc[wv][r] = v;
    }
    __syncthreads();
    if (tid < SROWS) {
      float y = fcs[0][tid] + fcs[1][tid] + fcs[2][tid] + fcs[3][tid] + p.fc_b[0];
      int smn = bid * SROWS + tid; int b = smn >> 12; int n = smn & 4095;
      p.out[((size_t)b * TP + t_out) * NS + n] = y;
      p.xp_s[smn] = y;
    }
    if (tid >= 64 && tid < 64 + CROWS) {
      int r = tid - 64;
      float y = cityfc[0][r] + cityfc[1][r] + cityfc[2][r] + cityfc[3][r] + p.c_fc_b[0];
      int cm = bid * CROWS + r; int b = cm >> 8; int n = cm & 255;
      p.out[(size_t)B * TP * NS + ((size_t)b * TP + t_out) * NC + n] = y;
      p.xp_c[cm] = y;
    }
  }
}

// ---------------- prologue kernels ----------------
__global__ __launch_bounds__(NTHR) void build_kernel(Params p) {
  build_tables(p, blockIdx.x, threadIdx.x, gridDim.x);
}
__global__ __launch_bounds__(NTHR) void ellv_kernel(Params p) {
  ellv_fill(p, blockIdx.x * NTHR + threadIdx.x, gridDim.x * NTHR);
}

extern "C" void kernel_launch(void* const* d_in, const int* in_sizes, int n_in,
                              void* d_out, int out_size, void* d_ws, size_t ws_size,
                              hipStream_t stream) {
  Params p;
  p.x_hist   = (const float*)d_in[0];
  p.feat_s   = (const float*)d_in[1];
  p.c_x_hist = (const float*)d_in[2];
  p.feat_c   = (const float*)d_in[3];
  p.adj_s    = (const float*)d_in[4];
  p.adj_c    = (const float*)d_in[5];
  p.afc      = (const float*)d_in[6];
  p.conv_w   = (const float*)d_in[7];
  p.conv_b   = (const float*)d_in[8];
  p.c_conv_w = (const float*)d_in[9];
  p.c_conv_b = (const float*)d_in[10];
  p.gru_wi   = (const float*)d_in[11];
  p.gru_wh   = (const float*)d_in[12];
  p.gru_bi   = (const float*)d_in[13];
  p.gru_bh   = (const float*)d_in[14];
  p.c_gru_wi = (const float*)d_in[15];
  p.c_gru_wh = (const float*)d_in[16];
  p.c_gru_bi = (const float*)d_in[17];
  p.c_gru_bh = (const float*)d_in[18];
  p.fc_w     = (const float*)d_in[19];
  p.fc_b     = (const float*)d_in[20];
  p.c_fc_w   = (const float*)d_in[21];
  p.c_fc_b   = (const float*)d_in[22];
  p.c2s_w    = (const float*)d_in[23];
  p.c2s_b    = (const float*)d_in[24];
  p.s2c_w    = (const float*)d_in[25];
  p.s2c_b    = (const float*)d_in[26];

  char* wp = (char*)d_ws;
  auto alloc = [&](size_t bytes) -> char* {
    char* q = wp;
    wp += (bytes + 255) & ~(size_t)255;
    return q;
  };
  p.deg_s  = (int*)alloc(NS * 4);
  p.dinv_s = (float*)alloc(NS * 4);
  p.ellc_s = (int*)alloc((size_t)NS * WS_ELL * 4);
  p.ellv_s = (float*)alloc((size_t)NS * WS_ELL * 4);
  p.deg_c  = (int*)alloc(NC * 4);
  p.dinv_c = (float*)alloc(NC * 4);
  p.ellc_c = (int*)alloc((size_t)NC * WS_ELL * 4);
  p.ellv_c = (float*)alloc((size_t)NC * WS_ELL * 4);
  p.degf   = (int*)alloc(NS * 4);
  p.ellf   = (int*)alloc((size_t)NS * WF_ELL * 4);
  p.degfT  = (int*)alloc(NC * 4);
  p.ellfT  = (int*)alloc((size_t)NC * WFT_ELL * 4);
  p.xg_s   = (float*)alloc((size_t)B * NS * G * 4);
  p.xg_c   = (float*)alloc((size_t)B * NC * G * 4);
  p.xp_s   = (float*)alloc((size_t)B * NS * 4);
  p.xp_c   = (float*)alloc((size_t)B * NC * 4);
  p.xsh    = (unsigned short*)alloc((size_t)B * NS * XCW * 2);
  p.xsl    = (unsigned short*)alloc((size_t)B * NS * XCW * 2);
  p.xch    = (unsigned short*)alloc((size_t)B * NC * XCW * 2);
  p.xcl    = (unsigned short*)alloc((size_t)B * NC * XCW * 2);
  p.wSh    = (unsigned short*)alloc((size_t)WFRAG * 2);
  p.wSl    = (unsigned short*)alloc((size_t)WFRAG * 2);
  p.wCh    = (unsigned short*)alloc((size_t)WFRAG * 2);
  p.wCl    = (unsigned short*)alloc((size_t)WFRAG * 2);
  p.wcvSh  = (unsigned short*)alloc((size_t)CVFRAG * 2);
  p.wcvSl  = (unsigned short*)alloc((size_t)CVFRAG * 2);
  p.wcvCh  = (unsigned short*)alloc((size_t)CVFRAG * 2);
  p.wcvCl  = (unsigned short*)alloc((size_t)CVFRAG * 2);
  p.aA_s   = (float*)alloc((size_t)NSTEP * B * NS * G * 4);   // 260 MB
  p.aA_c   = (float*)alloc((size_t)NSTEP * B * NC * G * 4);   // 16 MB
  p.out    = (float*)d_out;

  const bool big = ((size_t)(wp - (char*)d_ws) <= ws_size);

  build_kernel<<<2048, NTHR, 0, stream>>>(p);
  ellv_kernel<<<2048, NTHR, 0, stream>>>(p);
  if (big) {
    precompA2_kernel<<<NSTEP * 2048, NTHR, 0, stream>>>(p);
    for (int step = 0; step < NSTEP; step++) {
      int hist = (step < TH - 1) ? 1 : 0;
      stepA_lite_kernel<<<(B * NS + B * NC) / 4, NTHR, 0, stream>>>(p, step, hist);
      Params pb = p;
      if (hist) {
        pb.xg_s = p.aA_s + (size_t)step * (B * NS * G);
        pb.xg_c = p.aA_c + (size_t)step * (B * NC * G);
      }
      stepB_kernel<<<NBLK_B, NTHR, 0, stream>>>(pb, step, hist, step + 1);
    }
  } else {
    for (int step = 0; step < NSTEP; step++) {
      int hist = (step < TH - 1) ? 1 : 0;
      stepA_kernel<<<NBLK_A, NTHR, 0, stream>>>(p, step, hist);
      stepB_kernel<<<NBLK_B, NTHR, 0, stream>>>(p, step, hist, step + 1);
    }
  }
}

// Round 11
// 2797.051 us; speedup vs baseline: 1.0830x; 1.0341x over previous
//
#include <hip/hip_runtime.h>
#include <math.h>

typedef short bf16x8 __attribute__((ext_vector_type(8)));
typedef float f32x4 __attribute__((ext_vector_type(4)));

#define B 8
#define NS 4096
#define NC 256
#define TH 8
#define TP 24
#define T_ALL 32
#define DIN 28
#define DM 27
#define G 64
#define H 64
#define NG3 192
#define NSTEP 31

#define NTHR 256
// phase-B geometry: 512 blocks x 8 waves; each weight fragment fetched once per
// 64 rows (was 32) -> per-step weight L2 traffic halved (round-7 sensitivity).
#define NBLK_B 512
#define NTHR_B 512
#define BROWS 64          // station rows per B-block
#define BCROWS 4          // city rows per B-block
// phase-A geometry (precomp / fallback grid)
#define NBLK_A 2048
#define AS 16             // station rows per A-block
#define AR 17             // +1 city row

// xcat K layout: 0..27 x | 28..91 own_xg | 92..155 buf | 156..219 h | 220 bias | 221..223 pad
#define XCW 224
#define KIT 7             // K-iters of 32
#define NT 16             // N tiles (256 gate cols)
#define WFRAG (KIT*NT*64*8)   // 57344 bf16 per weight array
#define CVFRAG (2*4*64*8)     // 4096 bf16 per conv-weight array (K=64, N=64)

#define WS_ELL 64
#define WF_ELL 32
#define WFT_ELL 128

struct Params {
  const float *x_hist, *feat_s, *c_x_hist, *feat_c, *adj_s, *adj_c, *afc;
  const float *conv_w, *conv_b, *c_conv_w, *c_conv_b;
  const float *gru_wi, *gru_wh, *gru_bi, *gru_bh;
  const float *c_gru_wi, *c_gru_wh, *c_gru_bi, *c_gru_bh;
  const float *fc_w, *fc_b, *c_fc_w, *c_fc_b;
  const float *c2s_w, *c2s_b, *s2c_w, *s2c_b;
  int *deg_s, *ellc_s; float *ellv_s, *dinv_s;
  int *deg_c, *ellc_c; float *ellv_c, *dinv_c;
  int *degf, *ellf;
  int *degfT, *ellfT;
  float *xg_s, *xg_c, *xp_s, *xp_c;
  unsigned short *xsh, *xsl;         // [B*NS][XCW] bf16 hi/lo (pre-split A matrix)
  unsigned short *xch, *xcl;         // [B*NC][XCW] bf16 hi/lo
  unsigned short *wSh, *wSl, *wCh, *wCl;  // fragment-ordered Wcat2 bf16 hi/lo
  unsigned short *wcvSh, *wcvSl, *wcvCh, *wcvCl; // conv-weight fragments [K=64 x N=64]
  float *aA_s, *aA_c;                // [NSTEP][nodes][G]: hist->xg, pred->conv partial
  float *out;
};

__device__ __forceinline__ float sigm_(float x) { return 1.0f / (1.0f + expf(-x)); }

__device__ __forceinline__ unsigned short bf16rn(float f) {
  unsigned u = __float_as_uint(f);
  u += 0x7fffu + ((u >> 16) & 1u);
  return (unsigned short)(u >> 16);
}
__device__ __forceinline__ float bf16tof(unsigned short h) {
  return __uint_as_float(((unsigned)h) << 16);
}
__device__ __forceinline__ void split1(float f, unsigned short& hi, unsigned short& lo) {
  hi = bf16rn(f);
  lo = bf16rn(f - bf16tof(hi));
}

// LDS swizzle for precompA2 (kept from round 8: conflicts 1.7e7 -> 2.3e6)
__device__ __forceinline__ int sidx(int i, int c) {
  return i * 64 + (c ^ ((i & 7) << 3));
}

// Original Wcat[k][c], k in 0..156: rows 0..91 = wi, 92..155 = wh, 156 = bias.
// cols 0..127 = r,z (x+h fused); 128..191 = xn (wi only); 192..255 = hc (wh only).
__device__ float wcat_val(int k, int c, const float* wi, const float* wh,
                          const float* bi, const float* bh) {
  if (k < 92)  { return (c < 192) ? wi[k * NG3 + c] : 0.0f; }
  if (k < 156) {
    int kk = k - 92;
    if (c < 128) return wh[kk * NG3 + c];
    if (c < 192) return 0.0f;
    return wh[kk * NG3 + (c - 64)];
  }
  if (k == 156) {
    if (c < 128) return bi[c] + bh[c];
    if (c < 192) return bi[c];
    return bh[c - 64];
  }
  return 0.0f;
}

// Extended Wcat2[k][c], k in 0..223, folding the fuse stage.
// Zero structure (exploited in stepB): cols 128..191 have k 156..219 == 0
// (kiter 5 zero); cols 192..255 have k 0..155 == 0 (kiters 0..3 zero).
__device__ float wcat2_val(int k, int c, const float* wi, const float* wh,
                           const float* bi, const float* bh,
                           const float* wm, const float* bm) {
  if (k < 92) return wcat_val(k, c, wi, wh, bi, bh);
  if (k < 156) {
    int f = k - 92;
    float s = 0.0f;
    for (int g = 0; g < G; g++)
      s += wm[f * G + g] * wcat_val(28 + g, c, wi, wh, bi, bh);
    return s;
  }
  if (k < 220) return wcat_val(92 + (k - 156), c, wi, wh, bi, bh);
  if (k == 220) {
    float s = wcat_val(156, c, wi, wh, bi, bh);
    for (int g = 0; g < G; g++)
      s += bm[g] * wcat_val(28 + g, c, wi, wh, bi, bh);
    return s;
  }
  return 0.0f;
}

// x channel f of node n at global step (fallback stepA only).
__device__ __forceinline__ float xval(const Params& p, int sta, int hist, int step,
                                      int b, int n, int f) {
  if (f == 0) {
    if (hist) return sta ? p.x_hist[((size_t)b * TH + step) * NS + n]
                         : p.c_x_hist[((size_t)b * TH + step) * NC + n];
    return sta ? p.xp_s[b * NS + n] : p.xp_c[b * NC + n];
  }
  int tf = step + 1;
  return sta ? p.feat_s[(((size_t)b * T_ALL + tf) * NS + n) * DM + (f - 1)]
             : p.feat_c[(((size_t)b * T_ALL + tf) * NC + n) * DM + (f - 1)];
}

// ---------------- P0: ELL tables + weight fragment prep + xcat init ----------------
__device__ void build_tables(const Params& p, int bid, int tid, int nblk) {
  const int lane = tid & 63;
  const int gw = bid * 4 + (tid >> 6);
  const int nw = nblk * 4;

  for (int r = gw; r < NS; r += nw) {
    int base = 0;
    for (int n0 = 0; n0 < NS; n0 += 64) {
      int n = n0 + lane;
      float v = p.adj_s[(size_t)r * NS + n];
      bool fl = (v != 0.0f) && (n != r);
      unsigned long long m = __ballot(fl);
      if (fl) {
        int pos = base + (int)__popcll(m & ((1ull << lane) - 1ull));
        if (pos < WS_ELL) p.ellc_s[r * WS_ELL + pos] = n;
      }
      base += (int)__popcll(m);
    }
    int deg = base < WS_ELL ? base : WS_ELL;
    for (int s = deg + lane; s < WS_ELL; s += 64) p.ellc_s[r * WS_ELL + s] = 0;
    if (lane == 0) {
      p.deg_s[r] = deg;
      p.dinv_s[r] = base > 0 ? 1.0f / sqrtf((float)base) : 0.0f;
    }
  }
  for (int r = gw; r < NS; r += nw) {
    int base = 0;
    for (int n0 = 0; n0 < NC; n0 += 64) {
      int n = n0 + lane;
      bool fl = p.afc[(size_t)r * NC + n] != 0.0f;
      unsigned long long m = __ballot(fl);
      if (fl) {
        int pos = base + (int)__popcll(m & ((1ull << lane) - 1ull));
        if (pos < WF_ELL) p.ellf[r * WF_ELL + pos] = n;
      }
      base += (int)__popcll(m);
    }
    int deg = base < WF_ELL ? base : WF_ELL;
    for (int s = deg + lane; s < WF_ELL; s += 64) p.ellf[r * WF_ELL + s] = 0;
    if (lane == 0) p.degf[r] = deg;
  }
  for (int r = gw; r < NC; r += nw) {
    int base = 0;
    for (int n0 = 0; n0 < NC; n0 += 64) {
      int n = n0 + lane;
      float v = p.adj_c[(size_t)r * NC + n];
      bool fl = (v != 0.0f) && (n != r);
      unsigned long long m = __ballot(fl);
      if (fl) {
        int pos = base + (int)__popcll(m & ((1ull << lane) - 1ull));
        if (pos < WS_ELL) p.ellc_c[r * WS_ELL + pos] = n;
      }
      base += (int)__popcll(m);
    }
    int deg = base < WS_ELL ? base : WS_ELL;
    for (int s = deg + lane; s < WS_ELL; s += 64) p.ellc_c[r * WS_ELL + s] = 0;
    if (lane == 0) {
      p.deg_c[r] = deg;
      p.dinv_c[r] = base > 0 ? 1.0f / sqrtf((float)base) : 0.0f;
    }
  }
  for (int r = gw; r < NC; r += nw) {
    int base = 0;
    for (int n0 = 0; n0 < NS; n0 += 64) {
      int n = n0 + lane;
      bool fl = p.afc[(size_t)n * NC + r] != 0.0f;
      unsigned long long m = __ballot(fl);
      if (fl) {
        int pos = base + (int)__popcll(m & ((1ull << lane) - 1ull));
        if (pos < WFT_ELL) p.ellfT[r * WFT_ELL + pos] = n;
      }
      base += (int)__popcll(m);
    }
    int deg = base < WFT_ELL ? base : WFT_ELL;
    for (int s = deg + lane; s < WFT_ELL; s += 64) p.ellfT[r * WFT_ELL + s] = 0;
    if (lane == 0) p.degfT[r] = deg;
  }

  const int gid = bid * NTHR + tid, ntot = nblk * NTHR;
  // xp holds x_prev for the first pred step (= x_hist[:, TH-1])
  for (int i = gid; i < B * NS; i += ntot)
    p.xp_s[i] = p.x_hist[((size_t)(i / NS) * TH + (TH - 1)) * NS + (i % NS)];
  for (int i = gid; i < B * NC; i += ntot)
    p.xp_c[i] = p.c_x_hist[((size_t)(i / NC) * TH + (TH - 1)) * NC + (i % NC)];

  // GRU weight fragments: u -> (kiter q, tile t, lane l, j); k = q*32 + (l>>4)*8 + j
  for (int u = gid; u < WFRAG; u += ntot) {
    int j = u & 7, l = (u >> 3) & 63, t = (u >> 9) & 15, q = u >> 13;
    int k = q * 32 + ((l >> 4) << 3) + j;
    int c = t * 16 + (l & 15);
    float ws = wcat2_val(k, c, p.gru_wi, p.gru_wh, p.gru_bi, p.gru_bh, p.c2s_w, p.c2s_b);
    unsigned short hh, ll;
    split1(ws, hh, ll);
    p.wSh[u] = hh; p.wSl[u] = ll;
    float wc = wcat2_val(k, c, p.c_gru_wi, p.c_gru_wh, p.c_gru_bi, p.c_gru_bh, p.s2c_w, p.s2c_b);
    split1(wc, hh, ll);
    p.wCh[u] = hh; p.wCl[u] = ll;
  }
  // conv weight fragments (K=64: 0..27 = W0, 28..55 = W1, 56..63 = 0; N=64).
  for (int u = gid; u < CVFRAG; u += ntot) {
    int j = u & 7, l = (u >> 3) & 63, t = (u >> 9) & 3, q = u >> 11;
    int k = q * 32 + ((l >> 4) << 3) + j;
    int c = t * 16 + (l & 15);
    float vs = (k < 56) ? p.conv_w[k * G + c] : 0.0f;
    unsigned short hh, ll;
    split1(vs, hh, ll);
    p.wcvSh[u] = hh; p.wcvSl[u] = ll;
    float vc = (k < 56) ? p.c_conv_w[k * G + c] : 0.0f;
    split1(vc, hh, ll);
    p.wcvCh[u] = hh; p.wcvCl[u] = ll;
  }
  // xcat init: zeros (h state!), col 220 = 1.0 (bias)
  for (int u = gid; u < B * NS * XCW; u += ntot) {
    p.xsh[u] = ((u % XCW) == 220) ? 0x3F80 : 0;
    p.xsl[u] = 0;
  }
  for (int u = gid; u < B * NC * XCW; u += ntot) {
    p.xch[u] = ((u % XCW) == 220) ? 0x3F80 : 0;
    p.xcl[u] = 0;
  }
}

__device__ void ellv_fill(const Params& p, int gid, int ntot) {
  for (int s = gid; s < NS * WS_ELL; s += ntot) {
    int r = s >> 6, k = s & (WS_ELL - 1);
    p.ellv_s[s] = (k < p.deg_s[r]) ? -p.dinv_s[r] * p.dinv_s[p.ellc_s[s]] : 0.0f;
  }
  for (int s = gid; s < NC * WS_ELL; s += ntot) {
    int r = s >> 6, k = s & (WS_ELL - 1);
    p.ellv_c[s] = (k < p.deg_c[r]) ? -p.dinv_c[r] * p.dinv_c[p.ellc_c[s]] : 0.0f;
  }
}

// ---------------- precompA2: step-static cheb gather + MFMA conv for ALL steps ----------------
// grid: NSTEP*2048; block = (step, 16 stations + 1 city). Round-8 verified config.
__global__ __launch_bounds__(NTHR) void precompA2_kernel(Params p) {
  __shared__ unsigned short lh[AR * 64];
  __shared__ unsigned short llo[AR * 64];
  const int bid = blockIdx.x & 2047;
  const int step = blockIdx.x >> 11;
  const int hist = (step < TH - 1) ? 1 : 0;
  const int tid = threadIdx.x;
  const int b = bid >> 8;              // uniform per block

  // zero K-pad cols 56..63
  for (int u = tid; u < AR * 8; u += NTHR) {
    lh[sidx(u >> 3, 56 + (u & 7))] = 0;
    llo[sidx(u >> 3, 56 + (u & 7))] = 0;
  }

  for (int q = tid; q < AR * DIN; q += NTHR) {
    int i = q / DIN, f = q % DIN;
    int sta = (i < AS);
    int n;
    const int* cc; const float* vv; int trip;
    if (sta) {
      n = (bid * AS + i) & 4095;
      cc = &p.ellc_s[n * WS_ELL]; vv = &p.ellv_s[n * WS_ELL];
      trip = (p.deg_s[n] + 7) & ~7;
    } else {
      n = bid & 255;
      cc = &p.ellc_c[n * WS_ELL]; vv = &p.ellv_c[n * WS_ELL];
      trip = (p.deg_c[n] + 7) & ~7;
    }
    float xv = 0.0f, acc = 0.0f;
    if (f == 0) {
      if (hist) {
        const float* bh = sta ? (p.x_hist + ((size_t)b * TH + step) * NS)
                              : (p.c_x_hist + ((size_t)b * TH + step) * NC);
        xv = bh[n];
        for (int e = 0; e < trip; e += 8) {
          float xv8[8];
#pragma unroll
          for (int u = 0; u < 8; u++) xv8[u] = bh[cc[e + u]];
#pragma unroll
          for (int u = 0; u < 8; u++) acc += vv[e + u] * xv8[u];
        }
      }
      // pred: xv = acc = 0 (f=0 terms added per step in stepA_lite)
    } else {
      const float* bf = sta
        ? (p.feat_s + ((size_t)(b * T_ALL + step + 1) * NS) * DM + (f - 1))
        : (p.feat_c + ((size_t)(b * T_ALL + step + 1) * NC) * DM + (f - 1));
      xv = bf[(size_t)n * DM];
      for (int e = 0; e < trip; e += 8) {
        float xv8[8];
#pragma unroll
        for (int u = 0; u < 8; u++) xv8[u] = bf[(size_t)cc[e + u] * DM];
#pragma unroll
        for (int u = 0; u < 8; u++) acc += vv[e + u] * xv8[u];
      }
    }
    unsigned short hh, ll;
    split1(xv, hh, ll);
    lh[sidx(i, f)] = hh; llo[sidx(i, f)] = ll;
    split1(acc, hh, ll);
    lh[sidx(i, 28 + f)] = hh; llo[sidx(i, 28 + f)] = ll;
  }
  __syncthreads();

  // MFMA conv: wave wv owns output cols [wv*16, wv*16+16).
  const int l = tid & 63;
  const int wv = tid >> 6;
  f32x4 a1; f32x4 a2;
  a1[0] = 0.f; a1[1] = 0.f; a1[2] = 0.f; a1[3] = 0.f;
  a2[0] = 0.f; a2[1] = 0.f; a2[2] = 0.f; a2[3] = 0.f;
  const bf16x8* WVSh = (const bf16x8*)p.wcvSh;
  const bf16x8* WVSl = (const bf16x8*)p.wcvSl;
  const bf16x8* WVCh = (const bf16x8*)p.wcvCh;
  const bf16x8* WVCl = (const bf16x8*)p.wcvCl;
#pragma unroll
  for (int q = 0; q < 2; q++) {
    int kc = q * 32 + ((l >> 4) << 3);
    bf16x8 xh = *(const bf16x8*)&lh[sidx(l & 15, kc)];
    bf16x8 xl = *(const bf16x8*)&llo[sidx(l & 15, kc)];
    bf16x8 ch_, cl_;
    if ((l & 15) == 0) {
      ch_ = *(const bf16x8*)&lh[sidx(AS, kc)];
      cl_ = *(const bf16x8*)&llo[sidx(AS, kc)];
    } else {
#pragma unroll
      for (int j = 0; j < 8; j++) { ch_[j] = 0; cl_[j] = 0; }
    }
    int u = (q * 4 + wv) * 64 + l;
    bf16x8 bh_ = WVSh[u];
    bf16x8 bl_ = WVSl[u];
    a1 = __builtin_amdgcn_mfma_f32_16x16x32_bf16(xh, bh_, a1, 0, 0, 0);
    a1 = __builtin_amdgcn_mfma_f32_16x16x32_bf16(xl, bh_, a1, 0, 0, 0);
    a1 = __builtin_amdgcn_mfma_f32_16x16x32_bf16(xh, bl_, a1, 0, 0, 0);
    bf16x8 gh_ = WVCh[u];
    bf16x8 gl_ = WVCl[u];
    a2 = __builtin_amdgcn_mfma_f32_16x16x32_bf16(ch_, gh_, a2, 0, 0, 0);
    a2 = __builtin_amdgcn_mfma_f32_16x16x32_bf16(cl_, gh_, a2, 0, 0, 0);
    a2 = __builtin_amdgcn_mfma_f32_16x16x32_bf16(ch_, gl_, a2, 0, 0, 0);
  }

  const int g = wv * 16 + (l & 15);
  float* dst_s = p.aA_s + (size_t)step * (B * NS * G);
  float* dst_c = p.aA_c + (size_t)step * (B * NC * G);
  float bias = p.conv_b[g];
#pragma unroll
  for (int r = 0; r < 4; r++) {
    int row = ((l >> 4) << 2) + r;     // 0..15
    float v = a1[r] + bias;
    if (hist) v = sigm_(v);
    dst_s[(size_t)(bid * AS + row) * G + g] = v;
  }
  if ((l >> 4) == 0) {                  // city: C row 0 lives in lanes 0..15, reg 0
    float v = a2[0] + p.c_conv_b[g];
    if (hist) v = sigm_(v);
    dst_c[(size_t)bid * G + g] = v;
  }
}

// ---------------- stepA_lite: per-step dynamic completion ----------------
__global__ __launch_bounds__(NTHR) void stepA_lite_kernel(Params p, int step, int hist) {
  const int tid = threadIdx.x;
  const int l = tid & 63, wv = tid >> 6;
  const int wid = blockIdx.x * 4 + wv;
  if (wid < B * NS) {
    const int smn = wid, b = smn >> 12, n = smn & 4095;
    float x0 = hist ? p.x_hist[((size_t)b * TH + step) * NS + n] : p.xp_s[smn];
    float xg;
    const float* aA = p.aA_s + (size_t)step * (B * NS * G) + (size_t)smn * G;
    if (hist) {
      xg = aA[l];
    } else {
      float v = p.ellv_s[n * WS_ELL + l];
      int c = p.ellc_s[n * WS_ELL + l];
      float t = v * p.xp_s[b * NS + c];
#pragma unroll
      for (int m = 32; m; m >>= 1) t += __shfl_xor(t, m, 64);
      float acc = aA[l] + x0 * p.conv_w[l] + t * p.conv_w[DIN * G + l];
      xg = sigm_(acc);
      p.xg_s[(size_t)smn * G + l] = xg;
    }
    unsigned short hh, ll;
    split1(xg, hh, ll);
    size_t o = (size_t)smn * XCW;
    p.xsh[o + 28 + l] = hh; p.xsl[o + 28 + l] = ll;
    if (l < DIN) {
      float xv = (l == 0) ? x0
        : p.feat_s[(((size_t)b * T_ALL + step + 1) * NS + n) * DM + (l - 1)];
      split1(xv, hh, ll);
      p.xsh[o + l] = hh; p.xsl[o + l] = ll;
    }
  } else if (wid < B * NS + B * NC) {
    const int cm = wid - B * NS, b = cm >> 8, n = cm & 255;
    float x0 = hist ? p.c_x_hist[((size_t)b * TH + step) * NC + n] : p.xp_c[cm];
    float xg;
    const float* aA = p.aA_c + (size_t)step * (B * NC * G) + (size_t)cm * G;
    if (hist) {
      xg = aA[l];
    } else {
      float v = p.ellv_c[n * WS_ELL + l];
      int c = p.ellc_c[n * WS_ELL + l];
      float t = v * p.xp_c[b * NC + c];
#pragma unroll
      for (int m = 32; m; m >>= 1) t += __shfl_xor(t, m, 64);
      float acc = aA[l] + x0 * p.c_conv_w[l] + t * p.c_conv_w[DIN * G + l];
      xg = sigm_(acc);
      p.xg_c[(size_t)cm * G + l] = xg;
    }
    unsigned short hh, ll;
    split1(xg, hh, ll);
    size_t o = (size_t)cm * XCW;
    p.xch[o + 28 + l] = hh; p.xcl[o + 28 + l] = ll;
    if (l < DIN) {
      float xv = (l == 0) ? x0
        : p.feat_c[(((size_t)b * T_ALL + step + 1) * NC + n) * DM + (l - 1)];
      split1(xv, hh, ll);
      p.xch[o + l] = hh; p.xcl[o + l] = ll;
    }
  }
}

// ---------------- stepA (full, fallback path only) ----------------
__global__ __launch_bounds__(NTHR) void stepA_kernel(Params p, int step, int hist) {
  __shared__ float xa[AR][DIN];
  __shared__ float lx[AR][DIN];
  const int bid = blockIdx.x, tid = threadIdx.x;
  for (int q = tid; q < AR * DIN; q += NTHR) {
    int i = q / DIN, f = q % DIN;
    int sta = (i < AS);
    int b, n;
    const int* cc; const float* vv; int trip;
    if (sta) {
      int smn = bid * AS + i; b = smn >> 12; n = smn & 4095;
      cc = &p.ellc_s[n * WS_ELL]; vv = &p.ellv_s[n * WS_ELL];
      trip = (p.deg_s[n] + 7) & ~7;
    } else {
      b = bid >> 8; n = bid & 255;
      cc = &p.ellc_c[n * WS_ELL]; vv = &p.ellv_c[n * WS_ELL];
      trip = (p.deg_c[n] + 7) & ~7;
    }
    float xv = xval(p, sta, hist, step, b, n, f);
    xa[i][f] = xv;
    unsigned short hh, ll;
    split1(xv, hh, ll);
    if (sta) {
      size_t o = (size_t)(bid * AS + i) * XCW + f;
      p.xsh[o] = hh; p.xsl[o] = ll;
    } else {
      size_t o = (size_t)bid * XCW + f;
      p.xch[o] = hh; p.xcl[o] = ll;
    }
    float acc = 0.0f;
    for (int e = 0; e < trip; e += 8) {
      float xv8[8];
#pragma unroll
      for (int u = 0; u < 8; u++) xv8[u] = xval(p, sta, hist, step, b, cc[e + u], f);
#pragma unroll
      for (int u = 0; u < 8; u++) acc += vv[e + u] * xv8[u];
    }
    lx[i][f] = acc;
  }
  __syncthreads();
  for (int q = tid; q < AR * G; q += NTHR) {
    int i = q >> 6, g = q & 63;
    int sta = (i < AS);
    const float* W = sta ? p.conv_w : p.c_conv_w;
    float acc = (sta ? p.conv_b : p.c_conv_b)[g];
#pragma unroll 4
    for (int f = 0; f < DIN; f++)
      acc += xa[i][f] * W[f * G + g] + lx[i][f] * W[DIN * G + f * G + g];
    float s = sigm_(acc);
    unsigned short hh, ll;
    split1(s, hh, ll);
    if (sta) {
      p.xg_s[(size_t)(bid * AS + i) * G + g] = s;
      size_t o = (size_t)(bid * AS + i) * XCW + 28 + g;
      p.xsh[o] = hh; p.xsl[o] = ll;
    } else {
      p.xg_c[(size_t)bid * G + g] = s;
      size_t o = (size_t)bid * XCW + 28 + g;
      p.xch[o] = hh; p.xcl[o] = ll;
    }
  }
}

// ---------------- stepB: afc gather + fused MFMA GRU GEMM + epilogue ----------------
// grid: NBLK_B=512 blocks x 8 waves; block b covers stations [b*64,+64), cities [b*4,+4).
// Quad (wv>>2) owns station rows [quad*32, +32); wq (wv&3) is the verified column-split
// (all 4 gates of hidden j = wq*16+(l&15) wave-local). Quad 0 also carries 4 city rows.
// Weight fragments fetched once per 64 rows -> per-step weight L2 traffic halved.
__global__ __launch_bounds__(NTHR_B, 4) void stepB_kernel(Params p, int step, int hist, int idx) {
  __shared__ float cityfc[4][BCROWS];
  __shared__ float fcs[4][BROWS];
  const int bid = blockIdx.x, tid = threadIdx.x;
  unsigned short* xsh = p.xsh + (size_t)bid * BROWS * XCW;
  unsigned short* xsl = p.xsl + (size_t)bid * BROWS * XCW;
  unsigned short* xch = p.xch + (size_t)bid * BCROWS * XCW;
  unsigned short* xcl = p.xcl + (size_t)bid * BCROWS * XCW;

  // B1 stations (deg~4): buf -> xcat cols 92..155
#pragma unroll
  for (int k = 0; k < (BROWS * G) / NTHR_B; k++) {
    int q = tid + k * NTHR_B;
    int i = q >> 6, g = q & 63;
    int smn = bid * BROWS + i; int b = smn >> 12; int r = smn & 4095;
    int dg = p.degf[r];
    const int* cc = &p.ellf[r * WF_ELL];
    size_t bb = (size_t)b * NC;
    float acc = 0.0f;
    int e = 0;
    for (; e + 4 <= dg; e += 4) {
      acc += p.xg_c[(bb + cc[e]) * G + g] + p.xg_c[(bb + cc[e + 1]) * G + g]
           + p.xg_c[(bb + cc[e + 2]) * G + g] + p.xg_c[(bb + cc[e + 3]) * G + g];
    }
    for (; e < dg; e++) acc += p.xg_c[(bb + cc[e]) * G + g];
    unsigned short hh, ll;
    split1(acc, hh, ll);
    xsh[(size_t)i * XCW + 92 + g] = hh;
    xsl[(size_t)i * XCW + 92 + g] = ll;
  }
  // B1 cities (deg~64-96): 4 threads per (i,g); threads 0..255 rows 0..1, 256..511 rows 2..3
  {
    int half = tid >> 8;
    int t256 = tid & 255;
    int g = (t256 >> 2) & 63;
    int quar = t256 & 3;
#pragma unroll
    for (int c2 = 0; c2 < 2; c2++) {
      int ci = half * 2 + c2;
      int cm = bid * BCROWS + ci; int b = cm >> 8; int r = cm & 255;
      int dg = p.degfT[r];
      const int* cc = &p.ellfT[r * WFT_ELL];
      int dq = (dg + 3) >> 2;
      int e0 = quar * dq;
      int e1 = e0 + dq; if (e1 > dg) e1 = dg; if (e0 > dg) e0 = dg;
      size_t bb = (size_t)b * NS;
      float acc = 0.0f;
      int e = e0;
      for (; e + 4 <= e1; e += 4) {
        acc += p.xg_s[(bb + cc[e]) * G + g] + p.xg_s[(bb + cc[e + 1]) * G + g]
             + p.xg_s[(bb + cc[e + 2]) * G + g] + p.xg_s[(bb + cc[e + 3]) * G + g];
      }
      for (; e < e1; e++) acc += p.xg_s[(bb + cc[e]) * G + g];
      acc += __shfl_down(acc, 2, 4);
      acc += __shfl_down(acc, 1, 4);
      if (quar == 0) {
        unsigned short hh, ll;
        split1(acc, hh, ll);
        xch[(size_t)ci * XCW + 92 + g] = hh;
        xcl[(size_t)ci * XCW + 92 + g] = ll;
      }
    }
  }
  __syncthreads();

  // B3: MFMA GEMM gates[64(+4) x 256] = xcat[68 x 224] @ Wcat2[224 x 256]
  const int l = tid & 63;
  const int wv = tid >> 6;       // 0..7
  const int quad = wv >> 2;      // station row half
  const int wq = wv & 3;         // column-split index
  const int rowbase = quad * 32;
  f32x4 accS[8];   // [rt*4 + gate], rt = row-tile within quad (0..15 / 16..31)
  f32x4 accC[4];   // [gate], quad 0 only; city rows on lanes (l&15)<BCROWS
#pragma unroll
  for (int t = 0; t < 8; t++) { accS[t][0] = 0.f; accS[t][1] = 0.f; accS[t][2] = 0.f; accS[t][3] = 0.f; }
#pragma unroll
  for (int t = 0; t < 4; t++) { accC[t][0] = 0.f; accC[t][1] = 0.f; accC[t][2] = 0.f; accC[t][3] = 0.f; }
  const bf16x8* WSh = (const bf16x8*)p.wSh;
  const bf16x8* WSl = (const bf16x8*)p.wSl;
  const bf16x8* WCh = (const bf16x8*)p.wCh;
  const bf16x8* WCl = (const bf16x8*)p.wCl;

#pragma unroll
  for (int q = 0; q < KIT; q++) {
    int kc = q * 32 + ((l >> 4) << 3);
    bf16x8 aS0h = *(const bf16x8*)(xsh + (size_t)(rowbase + (l & 15)) * XCW + kc);
    bf16x8 aS0l = *(const bf16x8*)(xsl + (size_t)(rowbase + (l & 15)) * XCW + kc);
    bf16x8 aS1h = *(const bf16x8*)(xsh + (size_t)(rowbase + 16 + (l & 15)) * XCW + kc);
    bf16x8 aS1l = *(const bf16x8*)(xsl + (size_t)(rowbase + 16 + (l & 15)) * XCW + kc);
    bf16x8 aCh, aCl;
    if (quad == 0 && (l & 15) < BCROWS) {
      aCh = *(const bf16x8*)(xch + (size_t)(l & 15) * XCW + kc);
      aCl = *(const bf16x8*)(xcl + (size_t)(l & 15) * XCW + kc);
    } else {
#pragma unroll
      for (int j = 0; j < 8; j++) { aCh[j] = 0; aCl[j] = 0; }
    }
    int base = q * (NT * 64) + l;
#pragma unroll
    for (int tt = 0; tt < 4; tt++) {
      // structural-zero skip: tt=2 (xn) zero at kiter 5; tt=3 (hc) zero at kiters 0..3.
      if (tt == 2 && q == 5) continue;
      if (tt == 3 && q < 4) continue;
      int toff = base + (wq + tt * 4) * 64;
      bf16x8 wh_ = WSh[toff];
      bf16x8 wl_ = WSl[toff];
      accS[tt]     = __builtin_amdgcn_mfma_f32_16x16x32_bf16(aS0h, wh_, accS[tt], 0, 0, 0);
      accS[tt]     = __builtin_amdgcn_mfma_f32_16x16x32_bf16(aS0l, wh_, accS[tt], 0, 0, 0);
      accS[tt]     = __builtin_amdgcn_mfma_f32_16x16x32_bf16(aS0h, wl_, accS[tt], 0, 0, 0);
      accS[4 + tt] = __builtin_amdgcn_mfma_f32_16x16x32_bf16(aS1h, wh_, accS[4 + tt], 0, 0, 0);
      accS[4 + tt] = __builtin_amdgcn_mfma_f32_16x16x32_bf16(aS1l, wh_, accS[4 + tt], 0, 0, 0);
      accS[4 + tt] = __builtin_amdgcn_mfma_f32_16x16x32_bf16(aS1h, wl_, accS[4 + tt], 0, 0, 0);
      if (quad == 0) {
        bf16x8 ch_ = WCh[toff];
        bf16x8 cl_ = WCl[toff];
        accC[tt] = __builtin_amdgcn_mfma_f32_16x16x32_bf16(aCh, ch_, accC[tt], 0, 0, 0);
        accC[tt] = __builtin_amdgcn_mfma_f32_16x16x32_bf16(aCl, ch_, accC[tt], 0, 0, 0);
        accC[tt] = __builtin_amdgcn_mfma_f32_16x16x32_bf16(aCh, cl_, accC[tt], 0, 0, 0);
      }
    }
  }
  __syncthreads();   // all A-frag reads done before xcat cols are overwritten

  const int pred = !hist;
  const int t_out = step - (TH - 1);
  const int j = wq * 16 + (l & 15);
  const int upd = ((idx & ((1 << wq) - 1)) == 0);
  float fcacc[8];
  {
    float fwj = p.fc_w[j];
#pragma unroll
    for (int rt = 0; rt < 2; rt++) {
#pragma unroll
      for (int r = 0; r < 4; r++) {
        int row = rowbase + rt * 16 + ((l >> 4) << 2) + r;
        float rr = sigm_(accS[rt * 4 + 0][r]);
        float zz = sigm_(accS[rt * 4 + 1][r]);
        float nn = tanhf(accS[rt * 4 + 2][r] + rr * accS[rt * 4 + 3][r]);
        size_t o = (size_t)row * XCW + 156 + j;
        float ho = bf16tof(xsh[o]) + bf16tof(xsl[o]);
        float hn = upd ? ((1.0f - zz) * nn + zz * ho) : ho;
        unsigned short hh, ll;
        split1(hn, hh, ll);
        xsh[o] = hh; xsl[o] = ll;
        fcacc[rt * 4 + r] = fwj * hn;
      }
    }
  }
  float cfc[BCROWS] = {0.f, 0.f, 0.f, 0.f};
  if (quad == 0 && (l >> 4) == 0) {   // city rows 0..3 in regs 0..3, lanes 0..15
    float fwj = p.c_fc_w[j];
#pragma unroll
    for (int r = 0; r < BCROWS; r++) {
      float rr = sigm_(accC[0][r]);
      float zz = sigm_(accC[1][r]);
      float nn = tanhf(accC[2][r] + rr * accC[3][r]);
      size_t o = (size_t)r * XCW + 156 + j;
      float ho = bf16tof(xch[o]) + bf16tof(xcl[o]);
      float hn = upd ? ((1.0f - zz) * nn + zz * ho) : ho;
      unsigned short hh, ll;
      split1(hn, hh, ll);
      xch[o] = hh; xcl[o] = ll;
      cfc[r] = fwj * hn;
    }
  }
  if (pred) {
#pragma unroll
    for (int rt = 0; rt < 2; rt++) {
#pragma unroll
      for (int r = 0; r < 4; r++) {
        float v = fcacc[rt * 4 + r];
        v += __shfl_down(v, 8, 16);
        v += __shfl_down(v, 4, 16);
        v += __shfl_down(v, 2, 16);
        v += __shfl_down(v, 1, 16);
        if ((l & 15) == 0) fcs[wq][rowbase + rt * 16 + ((l >> 4) << 2) + r] = v;
      }
    }
    if (quad == 0) {
#pragma unroll
      for (int r = 0; r < BCROWS; r++) {
        float v = cfc[r];
        v += __shfl_down(v, 8, 16);
        v += __shfl_down(v, 4, 16);
        v += __shfl_down(v, 2, 16);
        v += __shfl_down(v, 1, 16);
        if (l == 0) cityfc[wq][r] = v;
      }
    }
    __syncthreads();
    if (tid < BROWS) {
      float y = fcs[0][tid] + fcs[1][tid] + fcs[2][tid] + fcs[3][tid] + p.fc_b[0];
      int smn = bid * BROWS + tid; int b = smn >> 12; int n = smn & 4095;
      p.out[((size_t)b * TP + t_out) * NS + n] = y;
      p.xp_s[smn] = y;
    }
    if (tid >= 64 && tid < 64 + BCROWS) {
      int r = tid - 64;
      float y = cityfc[0][r] + cityfc[1][r] + cityfc[2][r] + cityfc[3][r] + p.c_fc_b[0];
      int cm = bid * BCROWS + r; int b = cm >> 8; int n = cm & 255;
      p.out[(size_t)B * TP * NS + ((size_t)b * TP + t_out) * NC + n] = y;
      p.xp_c[cm] = y;
    }
  }
}

// ---------------- prologue kernels ----------------
__global__ __launch_bounds__(NTHR) void build_kernel(Params p) {
  build_tables(p, blockIdx.x, threadIdx.x, gridDim.x);
}
__global__ __launch_bounds__(NTHR) void ellv_kernel(Params p) {
  ellv_fill(p, blockIdx.x * NTHR + threadIdx.x, gridDim.x * NTHR);
}

extern "C" void kernel_launch(void* const* d_in, const int* in_sizes, int n_in,
                              void* d_out, int out_size, void* d_ws, size_t ws_size,
                              hipStream_t stream) {
  Params p;
  p.x_hist   = (const float*)d_in[0];
  p.feat_s   = (const float*)d_in[1];
  p.c_x_hist = (const float*)d_in[2];
  p.feat_c   = (const float*)d_in[3];
  p.adj_s    = (const float*)d_in[4];
  p.adj_c    = (const float*)d_in[5];
  p.afc      = (const float*)d_in[6];
  p.conv_w   = (const float*)d_in[7];
  p.conv_b   = (const float*)d_in[8];
  p.c_conv_w = (const float*)d_in[9];
  p.c_conv_b = (const float*)d_in[10];
  p.gru_wi   = (const float*)d_in[11];
  p.gru_wh   = (const float*)d_in[12];
  p.gru_bi   = (const float*)d_in[13];
  p.gru_bh   = (const float*)d_in[14];
  p.c_gru_wi = (const float*)d_in[15];
  p.c_gru_wh = (const float*)d_in[16];
  p.c_gru_bi = (const float*)d_in[17];
  p.c_gru_bh = (const float*)d_in[18];
  p.fc_w     = (const float*)d_in[19];
  p.fc_b     = (const float*)d_in[20];
  p.c_fc_w   = (const float*)d_in[21];
  p.c_fc_b   = (const float*)d_in[22];
  p.c2s_w    = (const float*)d_in[23];
  p.c2s_b    = (const float*)d_in[24];
  p.s2c_w    = (const float*)d_in[25];
  p.s2c_b    = (const float*)d_in[26];

  char* wp = (char*)d_ws;
  auto alloc = [&](size_t bytes) -> char* {
    char* q = wp;
    wp += (bytes + 255) & ~(size_t)255;
    return q;
  };
  p.deg_s  = (int*)alloc(NS * 4);
  p.dinv_s = (float*)alloc(NS * 4);
  p.ellc_s = (int*)alloc((size_t)NS * WS_ELL * 4);
  p.ellv_s = (float*)alloc((size_t)NS * WS_ELL * 4);
  p.deg_c  = (int*)alloc(NC * 4);
  p.dinv_c = (float*)alloc(NC * 4);
  p.ellc_c = (int*)alloc((size_t)NC * WS_ELL * 4);
  p.ellv_c = (float*)alloc((size_t)NC * WS_ELL * 4);
  p.degf   = (int*)alloc(NS * 4);
  p.ellf   = (int*)alloc((size_t)NS * WF_ELL * 4);
  p.degfT  = (int*)alloc(NC * 4);
  p.ellfT  = (int*)alloc((size_t)NC * WFT_ELL * 4);
  p.xg_s   = (float*)alloc((size_t)B * NS * G * 4);
  p.xg_c   = (float*)alloc((size_t)B * NC * G * 4);
  p.xp_s   = (float*)alloc((size_t)B * NS * 4);
  p.xp_c   = (float*)alloc((size_t)B * NC * 4);
  p.xsh    = (unsigned short*)alloc((size_t)B * NS * XCW * 2);
  p.xsl    = (unsigned short*)alloc((size_t)B * NS * XCW * 2);
  p.xch    = (unsigned short*)alloc((size_t)B * NC * XCW * 2);
  p.xcl    = (unsigned short*)alloc((size_t)B * NC * XCW * 2);
  p.wSh    = (unsigned short*)alloc((size_t)WFRAG * 2);
  p.wSl    = (unsigned short*)alloc((size_t)WFRAG * 2);
  p.wCh    = (unsigned short*)alloc((size_t)WFRAG * 2);
  p.wCl    = (unsigned short*)alloc((size_t)WFRAG * 2);
  p.wcvSh  = (unsigned short*)alloc((size_t)CVFRAG * 2);
  p.wcvSl  = (unsigned short*)alloc((size_t)CVFRAG * 2);
  p.wcvCh  = (unsigned short*)alloc((size_t)CVFRAG * 2);
  p.wcvCl  = (unsigned short*)alloc((size_t)CVFRAG * 2);
  p.aA_s   = (float*)alloc((size_t)NSTEP * B * NS * G * 4);   // 260 MB
  p.aA_c   = (float*)alloc((size_t)NSTEP * B * NC * G * 4);   // 16 MB
  p.out    = (float*)d_out;

  const bool big = ((size_t)(wp - (char*)d_ws) <= ws_size);

  build_kernel<<<2048, NTHR, 0, stream>>>(p);
  ellv_kernel<<<2048, NTHR, 0, stream>>>(p);
  if (big) {
    precompA2_kernel<<<NSTEP * 2048, NTHR, 0, stream>>>(p);
    for (int step = 0; step < NSTEP; step++) {
      int hist = (step < TH - 1) ? 1 : 0;
      stepA_lite_kernel<<<(B * NS + B * NC) / 4, NTHR, 0, stream>>>(p, step, hist);
      Params pb = p;
      if (hist) {
        pb.xg_s = p.aA_s + (size_t)step * (B * NS * G);
        pb.xg_c = p.aA_c + (size_t)step * (B * NC * G);
      }
      stepB_kernel<<<NBLK_B, NTHR_B, 0, stream>>>(pb, step, hist, step + 1);
    }
  } else {
    for (int step = 0; step < NSTEP; step++) {
      int hist = (step < TH - 1) ? 1 : 0;
      stepA_kernel<<<NBLK_A, NTHR, 0, stream>>>(p, step, hist);
      stepB_kernel<<<NBLK_B, NTHR_B, 0, stream>>>(p, step, hist, step + 1);
    }
  }
}